// Round 19
// baseline (173.933 us; speedup 1.0000x reference)
//
#include <hip/hip_runtime.h>
#include <hip/hip_bf16.h>

// SelfAttention: x[8,256,48,48] fp32; wq/wk/wv[256,256] fp32.
// out = x + attn(softmax(q^T k), v). B=8, C=256, N=2304. fp16 MFMA path.
//
// R18 post-mortem: attn loop at structural plateau (2 waves/SIMD pinned by
// VGPR steps 128/256; Q-to-LDS alternative is LDS-bound; fp8 fails numerics).
// Untested lever: block-granularity TAIL (1152 blocks / 512 slots = 2.25
// gens + ~1 gen drain). R19: splits=8 (2304 blocks, NT=9, T_b halved;
// combine generalized to dynamic splits) + THR=15 (P<=2^15 fp16-safe,
// fewer wave-wide rescales). Pre-commit: wash => declare ceiling.
//
// K_swz[kb][ks 16][hi 2][key 32][j 8]: short off = kb*8192+ks*512+hi*256+key*8+j
// V_swz[kb][ct 8][kh 2][hi 2][c 32][j 8]: off = kb*8192+ct*1024+kh*512+hi*256+c*8+j
// weights frag-ordered: off = ot*4096 + ks*512 + g*128 + i*8 + j
// ws: wq/wk/wv fp16 [65536 ea]; Qt [B*N*C] token-major; Ksw,Vsw [B*N*C];
//     P fp16 [splits][B][C][N]; ml f32 [splits][B][N][2].

#define DEVI __device__ __forceinline__

typedef _Float16 f16x8 __attribute__((ext_vector_type(8)));
typedef float f32x4 __attribute__((ext_vector_type(4)));
typedef float f32x16 __attribute__((ext_vector_type(16)));

constexpr int Bn = 8, Cn = 256, Nn = 48 * 48;   // 2304

#if defined(__has_builtin)
#if __has_builtin(__builtin_amdgcn_permlane32_swap)
#define HAVE_PL32 1
#endif
#endif

DEVI unsigned short f2h(float f) {
  _Float16 h = (_Float16)f;
  return __builtin_bit_cast(unsigned short, h);
}
DEVI float h2f(unsigned short u) {
  return (float)__builtin_bit_cast(_Float16, u);
}
DEVI unsigned pk2(float a, float b) {           // pack 2 f32 -> f16x2 (RTZ)
  auto h = __builtin_amdgcn_cvt_pkrtz(a, b);
  return __builtin_bit_cast(unsigned, h);
}
DEVI void stage16(const unsigned short* g, unsigned short* l) {
  __builtin_amdgcn_global_load_lds(
      (const __attribute__((address_space(1))) void*)g,
      (__attribute__((address_space(3))) void*)l, 16, 0, 0);
}
// permlane32_swap(a,b): a' = {a.lo, b.lo}; b' = {a.hi, b.hi}
DEVI void pl32swap(unsigned& a, unsigned& b) {
#ifdef HAVE_PL32
  auto r = __builtin_amdgcn_permlane32_swap(a, b, false, false);
  a = r[0];
  b = r[1];
#else
  unsigned sa = __shfl_xor(a, 32), sb = __shfl_xor(b, 32);
  bool hb = (threadIdx.x & 32) != 0;
  a = hb ? sb : a;
  b = hb ? b : sa;
#endif
}
DEVI void pl32swapf(float& a, float& b) {
  unsigned ua = __builtin_bit_cast(unsigned, a);
  unsigned ub = __builtin_bit_cast(unsigned, b);
  pl32swap(ua, ub);
  a = __builtin_bit_cast(float, ua);
  b = __builtin_bit_cast(float, ub);
}

#define MFMA16(a, b, c) __builtin_amdgcn_mfma_f32_16x16x32_f16((a), (b), (c), 0, 0, 0)
#define MFMA32(a, b, c) __builtin_amdgcn_mfma_f32_32x32x16_f16((a), (b), (c), 0, 0, 0)

// ---- weights -> fp16, FRAG-ORDERED: dst[ot*4096 + ks*512 + g*128 + i*8 + j]
//      = w[oc = 16ot + i][c = 32ks + 8g + j]  (wq pre-scaled by log2e)
__global__ __launch_bounds__(256) void cvt_w(const float* __restrict__ wq,
                                             const float* __restrict__ wk,
                                             const float* __restrict__ wv,
                                             unsigned short* __restrict__ o) {
  int idx = blockIdx.x * 256 + threadIdx.x;     // 3*65536 total
  int mat = idx >> 16, off = idx & 65535;
  const float* s = (mat == 0) ? wq : (mat == 1) ? wk : wv;
  int ot = off >> 12, ks = (off >> 9) & 7, g = (off >> 7) & 3;
  int i = (off >> 3) & 15, j = off & 7;
  float v = s[(ot * 16 + i) * Cn + ks * 32 + g * 8 + j];
  if (mat == 0) v *= 1.44269504f;               // exp2-domain softmax
  o[idx] = f2h(v);
}

// ---------------- QKV projection (z-merged, n-tile 32, frag-ordered w) -----
// grid (N/32, B) = (72, 8), 256 thr = 4 waves. th = w&1 (token half).
__global__ __launch_bounds__(256) void qkv_proj(
    const float* __restrict__ x,
    const unsigned short* __restrict__ wqb, const unsigned short* __restrict__ wkb,
    const unsigned short* __restrict__ wvb,
    unsigned short* __restrict__ Qt, unsigned short* __restrict__ Ksw,
    unsigned short* __restrict__ Vsw) {
  __shared__ unsigned short xT[32][264];        // [token][c], +8 pad
  const int tid = threadIdx.x;
  const int n0 = blockIdx.x * 32;
  const int b = blockIdx.y;
  const float* xb = x + (size_t)b * Cn * Nn;
  {
    int c0 = tid >> 3;
    int nn = (tid & 7) * 4;
#pragma unroll
    for (int it = 0; it < 8; ++it) {
      int c = c0 + 32 * it;
      float4 v = *(const float4*)(xb + (size_t)c * Nn + n0 + nn);
      xT[nn + 0][c] = f2h(v.x);
      xT[nn + 1][c] = f2h(v.y);
      xT[nn + 2][c] = f2h(v.z);
      xT[nn + 3][c] = f2h(v.w);
    }
  }
  __syncthreads();
  const int lane = tid & 63, w = tid >> 6;
  const int i = lane & 15, g = lane >> 4;
  const int th = w & 1;                         // token half (constant both phases)
  const int wlo = g * 128 + i * 8;              // frag-ordered lane offset
  f16x8 xf[8];                                  // x^T frags for tokens th*16..+15
#pragma unroll
  for (int ks = 0; ks < 8; ++ks)
    xf[ks] = *(const f16x8*)(&xT[th * 16 + i][32 * ks + 8 * g]);

  const int kb0 = n0 >> 5;                      // == blockIdx.x (32-token chunk)
  // ---- phase 1: Q (w<2) or K (w>=2), 16 ot-tiles ----
  if (w < 2) {                                  // Q -> token-major [N][C]
    const size_t tokbase = (size_t)b * Nn + n0 + th * 16;
    for (int ot = 0; ot < 16; ++ot) {
      f32x4 acc = {0.f, 0.f, 0.f, 0.f};
      const unsigned short* wr = wqb + ot * 4096 + wlo;
#pragma unroll
      for (int ks = 0; ks < 8; ++ks)
        acc = MFMA16(xf[ks], *(const f16x8*)(wr + 512 * ks), acc);
#pragma unroll
      for (int r = 0; r < 4; ++r)
        Qt[(tokbase + 4 * g + r) * Cn + ot * 16 + i] = f2h(acc[r]);
    }
  } else {                                      // K -> frag-swizzled
    unsigned short* kout = Ksw + (size_t)b * Nn * Cn + (size_t)kb0 * 8192
                         + ((i >> 3) & 1) * 256 + (i & 7);
    const int keyb = th * 16 + 4 * g;           // + r
    for (int ot = 0; ot < 16; ++ot) {
      f32x4 acc = {0.f, 0.f, 0.f, 0.f};
      const unsigned short* wr = wkb + ot * 4096 + wlo;
#pragma unroll
      for (int ks = 0; ks < 8; ++ks)
        acc = MFMA16(xf[ks], *(const f16x8*)(wr + 512 * ks), acc);
#pragma unroll
      for (int r = 0; r < 4; ++r)
        kout[ot * 512 + (keyb + r) * 8] = f2h(acc[r]);
    }
  }
  // ---- phase 2: V, 8 ot-tiles per wave; acc[r]=V[c=ot*16+4g+r][tok=th*16+i]
  {
    unsigned short* vout = Vsw + (size_t)b * Nn * Cn + (size_t)kb0 * 8192
                         + th * 512 + ((i >> 3) & 1) * 256 + (i & 7);
    const int otb = (w >> 1) * 8;
    for (int oo = 0; oo < 8; ++oo) {
      const int ot = otb + oo;
      f32x4 acc = {0.f, 0.f, 0.f, 0.f};
      const unsigned short* wr = wvb + ot * 4096 + wlo;
#pragma unroll
      for (int ks = 0; ks < 8; ++ks)
        acc = MFMA16(*(const f16x8*)(wr + 512 * ks), xf[ks], acc);
#pragma unroll
      for (int r = 0; r < 4; ++r) {
        int c = ot * 16 + 4 * g + r;
        vout[(c >> 5) * 1024 + (c & 31) * 8] = f2h(acc[r]);
      }
    }
  }
}

// ---- flash attention: split-K, K 3-buf LDS, V reg-streamed, T15 x2 --------
// grid Bn*splits*36, 256 thr = 4 waves = 2 q-tiles(32q) x 2 c-halves(128c).
// LDS 48KB = 3 x 16KB K bufs, staged 2-ahead. Mid-iter barrier after explicit
// vmcnt(4). QK^T(t+1) (single chain) overlaps SM(t); dA/dB ping-pong.
__global__ __launch_bounds__(256, 2) void attn_split(
    const unsigned short* __restrict__ Qt, const unsigned short* __restrict__ Ksw,
    const unsigned short* __restrict__ Vsw,
    unsigned short* __restrict__ P, float* __restrict__ ml, int splits) {
  __shared__ unsigned short smem[24576];        // 48 KB
  const int nblk = gridDim.x;                   // divisible by 8
  const int cpx = nblk >> 3;
  const int swz = (blockIdx.x & 7) * cpx + (blockIdx.x >> 3);  // XCD chunked
  const int per_b = splits * 36;
  const int b = swz / per_b;
  const int rem = swz - b * per_b;
  const int s = rem / 36;
  const int qt = rem - s * 36;
  const int n0 = qt * 64;
  const int kn = Nn / splits;
  const int kb0 = (s * kn) >> 5;                // first 32-key chunk id
  const int NT = kn / 32;                       // 9 at splits=8

  const int tid = threadIdx.x, lane = tid & 63, w = tid >> 6;
  const int q = lane & 31, hi = lane >> 5;
  const int qtile = w & 1, chalf = w >> 1;
  const int q0 = n0 + qtile * 32;

  const unsigned short* Ksrc = Ksw + (size_t)b * Nn * Cn + tid * 8;
  const unsigned short* Vb = Vsw + (size_t)b * Nn * Cn + hi * 256 + q * 8
                           + (size_t)chalf * 4096;

  auto stageK = [&](int kbid, int buf) {        // linear 16KB chunk copy
    unsigned short* dst = smem + buf * 8192 + w * 512;
    const unsigned short* src = Ksrc + (size_t)kbid * 8192;
#pragma unroll
    for (int c4 = 0; c4 < 4; ++c4)
      stage16(src + c4 * 2048, dst + c4 * 2048);
  };

  const int lo = hi * 512 + q * 16;             // byte offset within frag row

  // resident Q B-frags: lane: query=q, c = 16*ks + 8*hi + j
  const unsigned short* Qb = Qt + ((size_t)b * Nn + q0 + q) * Cn + 8 * hi;
  f16x8 qf[16];
#pragma unroll
  for (int ks = 0; ks < 16; ++ks) qf[ks] = *(const f16x8*)(Qb + 16 * ks);

  auto qkt = [&](int buf) -> f32x16 {           // single-chain QK^T
    const char* KsB = (const char*)smem + buf * 16384;
    f32x16 dd = (f32x16)(0.f);
#pragma unroll
    for (int ks = 0; ks < 16; ++ks)
      dd = MFMA32(*(const f16x8*)(KsB + ks * 1024 + lo), qf[ks], dd);
    return dd;
  };

  stageK(kb0, 0);                               // prologue: 2-ahead
  stageK(kb0 + 1, 1);

  f32x16 acc[4];                                // channels chalf*128 .. +128
#pragma unroll
  for (int ct = 0; ct < 4; ++ct) acc[ct] = (f32x16)(0.f);
  float m = -1e30f, lsum = 0.f;                 // lsum: per-half partial

  asm volatile("s_waitcnt vmcnt(4)" ::: "memory");   // own K0 landed (K1 in flight)
  __builtin_amdgcn_sched_barrier(0);
  __builtin_amdgcn_s_barrier();                 // all waves' K0 landed

  auto body = [&](int t, f32x16& dcur, f32x16& dnx) {
    const unsigned short* vp = Vb + (size_t)(kb0 + t) * 8192;
    // ---- V frags for this iter: all 8, issued first ----
    f16x8 vf[8];
#pragma unroll
    for (int ct = 0; ct < 4; ++ct) {
      vf[2 * ct] = *(const f16x8*)(vp + ct * 1024);
      vf[2 * ct + 1] = *(const f16x8*)(vp + ct * 1024 + 512);
    }
    __builtin_amdgcn_sched_barrier(0);          // keep V issues before K stage
    if (t + 2 < NT) stageK(kb0 + t + 2, (t + 2) % 3);

    // vmcnt(4): confirms vf(t) + stageK(t+1) (in-order); leaves stageK(t+2).
    asm volatile("s_waitcnt vmcnt(4)" ::: "memory");
    __builtin_amdgcn_sched_barrier(0);
    __builtin_amdgcn_s_barrier();               // buf(t+1) now block-wide safe

    // ---- QK^T(t+1) on MFMA pipe, overlapped with SM(t) on VALU pipe ----
    if (t + 1 < NT) dnx = qkt((t + 1) % 3);

    // ---- online softmax (log2 domain) on dcur = scores(t) ----
    float u0 = fmaxf(dcur[0], dcur[1]),   u1 = fmaxf(dcur[2], dcur[3]);
    float u2 = fmaxf(dcur[4], dcur[5]),   u3 = fmaxf(dcur[6], dcur[7]);
    float u4 = fmaxf(dcur[8], dcur[9]),   u5 = fmaxf(dcur[10], dcur[11]);
    float u6 = fmaxf(dcur[12], dcur[13]), u7 = fmaxf(dcur[14], dcur[15]);
    float mx = fmaxf(fmaxf(fmaxf(u0, u1), fmaxf(u2, u3)),
                     fmaxf(fmaxf(u4, u5), fmaxf(u6, u7)));
    {                                           // cross-half max (order-robust)
      float mc = mx;
      pl32swapf(mc, mx);
      mx = fmaxf(mc, mx);
    }
    if (__any(mx > m + 15.f)) {                 // defer-max (P <= 2^15 fp16-safe)
      float mnew = fmaxf(m, mx);
      float alpha = __builtin_exp2f(m - mnew);
      m = mnew;
      lsum *= alpha;
#pragma unroll
      for (int ct = 0; ct < 4; ++ct)
#pragma unroll
        for (int r = 0; r < 16; ++r) acc[ct][r] *= alpha;
    }
    float p[16];
#pragma unroll
    for (int r = 0; r < 16; ++r) p[r] = __builtin_exp2f(dcur[r] - m);
    float cs = 0.f;
#pragma unroll
    for (int r = 0; r < 16; ++r) cs += p[r];
    lsum += cs;                                 // per-half partial (no shfl)

    // ---- P -> B-frags: swap(A0,A2) yields (pb0.u[0], pb0.u[2]) etc ----
    unsigned A0 = pk2(p[0], p[1]), A1 = pk2(p[2], p[3]);
    unsigned A2 = pk2(p[4], p[5]), A3 = pk2(p[6], p[7]);
    unsigned A4 = pk2(p[8], p[9]), A5 = pk2(p[10], p[11]);
    unsigned A6 = pk2(p[12], p[13]), A7 = pk2(p[14], p[15]);
    pl32swap(A0, A2);
    pl32swap(A1, A3);
    pl32swap(A4, A6);
    pl32swap(A5, A7);
    union { unsigned u[4]; f16x8 v; } pb0, pb1;
    pb0.u[0] = A0; pb0.u[1] = A1; pb0.u[2] = A2; pb0.u[3] = A3;
    pb1.u[0] = A4; pb1.u[1] = A5; pb1.u[2] = A6; pb1.u[3] = A7;

    // ---- PV: 4 c-tiles of this wave's c-half, V from registers ----
    __builtin_amdgcn_s_setprio(1);
    acc[0] = MFMA32(vf[0], pb0.v, acc[0]);
    acc[0] = MFMA32(vf[1], pb1.v, acc[0]);
    acc[1] = MFMA32(vf[2], pb0.v, acc[1]);
    acc[1] = MFMA32(vf[3], pb1.v, acc[1]);
    acc[2] = MFMA32(vf[4], pb0.v, acc[2]);
    acc[2] = MFMA32(vf[5], pb1.v, acc[2]);
    acc[3] = MFMA32(vf[6], pb0.v, acc[3]);
    acc[3] = MFMA32(vf[7], pb1.v, acc[3]);
    __builtin_amdgcn_s_setprio(0);
  };

  f32x16 dA = qkt(0), dB;                       // scores for tile 0
  int t = 0;
  for (; t + 1 < NT; t += 2) {                  // pairs (ping-pong)
    body(t, dA, dB);
    body(t + 1, dB, dA);
  }
  if (t < NT) body(t, dA, dB);                  // odd-NT tail (splits=8: NT=9)

  // ---- epilogue: combine half-sums (order-robust), O_s = acc/lsum ----
  {
    float lc = lsum;
    pl32swapf(lc, lsum);
    lsum += lc;
  }
  const float rl = 1.f / lsum;
  unsigned short* Pb = P + (size_t)(s * Bn + b) * Cn * Nn;
#pragma unroll
  for (int ct = 0; ct < 4; ++ct)
#pragma unroll
    for (int r = 0; r < 16; ++r) {
      int c = 32 * (chalf * 4 + ct) + (r & 3) + 8 * (r >> 2) + 4 * hi;
      Pb[(size_t)c * Nn + q0 + q] = f2h(acc[ct][r] * rl);
    }
  if (!hi && !chalf)
    *(float2*)&ml[((size_t)(s * Bn + b) * Nn + q0 + q) * 2] = make_float2(m, lsum);
}

// ---------------- combine partials + residual (dynamic splits <= 8) --------
// out = x + sum_s w_s * O_s,  w_s = 2^(m_s - M) * l_s / sum(2^(m_s-M) l_s).
__global__ __launch_bounds__(256) void combine_k(
    const float* __restrict__ x, const unsigned short* __restrict__ P,
    const float* __restrict__ ml, float* __restrict__ out, int splits) {
  __shared__ float sc[8][32];
  const int tpb = Nn / 32;                      // 72
  const int b = blockIdx.x / tpb;
  const int n0 = (blockIdx.x - b * tpb) * 32;
  const int t = threadIdx.x;
  if (t < 32) {
    const int n = n0 + t;
    const size_t sstr = (size_t)Bn * Nn * 2;
    const float* mlb = ml + ((size_t)b * Nn + n) * 2;
    float M = -1e30f;
    for (int s2 = 0; s2 < splits; ++s2) M = fmaxf(M, mlb[s2 * sstr]);
    float den = 0.f;
    for (int s2 = 0; s2 < splits; ++s2) {
      float g = __builtin_exp2f(mlb[s2 * sstr] - M) * mlb[s2 * sstr + 1];
      sc[s2][t] = g;
      den += g;
    }
    float rden = 1.f / den;
    for (int s2 = 0; s2 < splits; ++s2) sc[s2][t] *= rden;
  }
  __syncthreads();
  const int nl4 = (t & 7) * 4, c0 = t >> 3;
  const size_t pstr = (size_t)Bn * Cn * Nn;     // shorts per split
  const float* xb = x + (size_t)b * Cn * Nn;
  float* ob = out + (size_t)b * Cn * Nn;
#pragma unroll
  for (int k = 0; k < 8; ++k) {
    const int c = c0 + 32 * k;
    const unsigned short* Pp = P + ((size_t)b * Cn + c) * Nn + n0 + nl4;
    f32x4 a = {0.f, 0.f, 0.f, 0.f};
    for (int s2 = 0; s2 < splits; ++s2) {
      ushort4 ph = *(const ushort4*)(Pp + s2 * pstr);
      f32x4 pv = {h2f(ph.x), h2f(ph.y), h2f(ph.z), h2f(ph.w)};
      f32x4 sw = {sc[s2][nl4 + 0], sc[s2][nl4 + 1], sc[s2][nl4 + 2], sc[s2][nl4 + 3]};
      a += sw * pv;
    }
    f32x4 xv = *(const f32x4*)(xb + (size_t)c * Nn + n0 + nl4);
    *(f32x4*)(ob + (size_t)c * Nn + n0 + nl4) = xv + a;
  }
}

extern "C" void kernel_launch(void* const* d_in, const int* in_sizes, int n_in,
                              void* d_out, int out_size, void* d_ws, size_t ws_size,
                              hipStream_t stream) {
  const float* x = (const float*)d_in[0];
  const float* wq = (const float*)d_in[1];
  const float* wk = (const float*)d_in[2];
  const float* wv = (const float*)d_in[3];
  float* out = (float*)d_out;

  unsigned short* wqb = (unsigned short*)d_ws;
  unsigned short* wkb = wqb + Cn * Cn;
  unsigned short* wvb = wkb + Cn * Cn;
  unsigned short* Qt = wvb + Cn * Cn;
  unsigned short* Ksw = Qt + (size_t)Bn * Nn * Cn;
  unsigned short* Vsw = Ksw + (size_t)Bn * Nn * Cn;
  unsigned short* P = Vsw + (size_t)Bn * Nn * Cn;

  const size_t baseB = (size_t)(3 * Cn * Cn + 3 * (size_t)Bn * Nn * Cn) * 2;
  const size_t perSplitB = (size_t)Bn * Nn * Cn * 2 + (size_t)Bn * Nn * 2 * 4;

  int splits = 1;
  if (baseB + 8 * perSplitB <= ws_size) splits = 8;
  else if (baseB + 4 * perSplitB <= ws_size) splits = 4;
  else if (baseB + 2 * perSplitB <= ws_size) splits = 2;

  float* ml = (float*)(P + (size_t)splits * Bn * Nn * Cn);

  hipLaunchKernelGGL(cvt_w, dim3(3 * Cn * Cn / 256), dim3(256), 0, stream, wq, wk, wv, wqb);
  hipLaunchKernelGGL(qkv_proj, dim3(Nn / 32, Bn), dim3(256), 0, stream,
                     x, wqb, wkb, wvb, Qt, Ksw, Vsw);
  hipLaunchKernelGGL(attn_split, dim3(Bn * splits * 36), dim3(256), 0, stream,
                     Qt, Ksw, Vsw, P, ml, splits);
  hipLaunchKernelGGL(combine_k, dim3(Bn * Nn / 32), dim3(256), 0, stream,
                     x, P, ml, out, splits);
}

// Round 20
// 164.871 us; speedup vs baseline: 1.0550x; 1.0550x over previous
//
#include <hip/hip_runtime.h>
#include <hip/hip_bf16.h>

// SelfAttention: x[8,256,48,48] fp32; wq/wk/wv[256,256] fp32.
// out = x + attn(softmax(q^T k), v). B=8, C=256, N=2304. fp16 MFMA path.
//
// R19 post-mortem: splits=8 regressed (per-block fixed costs x2 + combine
// P-traffic x2 beat the tail savings; tail was already hidden by 2.25-gen
// overlap). R20: exact revert to the R18 best (163.3us): splits=4, NT=18,
// THR=12, T15 ping-pong pipeline, single-chain QK^T.
//
// K_swz[kb][ks 16][hi 2][key 32][j 8]: short off = kb*8192+ks*512+hi*256+key*8+j
// V_swz[kb][ct 8][kh 2][hi 2][c 32][j 8]: off = kb*8192+ct*1024+kh*512+hi*256+c*8+j
// weights frag-ordered: off = ot*4096 + ks*512 + g*128 + i*8 + j
// ws: wq/wk/wv fp16 [65536 ea]; Qt [B*N*C] token-major; Ksw,Vsw [B*N*C];
//     P fp16 [splits][B][C][N]; ml f32 [splits][B][N][2].

#define DEVI __device__ __forceinline__

typedef _Float16 f16x8 __attribute__((ext_vector_type(8)));
typedef float f32x4 __attribute__((ext_vector_type(4)));
typedef float f32x16 __attribute__((ext_vector_type(16)));

constexpr int Bn = 8, Cn = 256, Nn = 48 * 48;   // 2304

#if defined(__has_builtin)
#if __has_builtin(__builtin_amdgcn_permlane32_swap)
#define HAVE_PL32 1
#endif
#endif

DEVI unsigned short f2h(float f) {
  _Float16 h = (_Float16)f;
  return __builtin_bit_cast(unsigned short, h);
}
DEVI float h2f(unsigned short u) {
  return (float)__builtin_bit_cast(_Float16, u);
}
DEVI unsigned pk2(float a, float b) {           // pack 2 f32 -> f16x2 (RTZ)
  auto h = __builtin_amdgcn_cvt_pkrtz(a, b);
  return __builtin_bit_cast(unsigned, h);
}
DEVI void stage16(const unsigned short* g, unsigned short* l) {
  __builtin_amdgcn_global_load_lds(
      (const __attribute__((address_space(1))) void*)g,
      (__attribute__((address_space(3))) void*)l, 16, 0, 0);
}
// permlane32_swap(a,b): a' = {a.lo, b.lo}; b' = {a.hi, b.hi}
DEVI void pl32swap(unsigned& a, unsigned& b) {
#ifdef HAVE_PL32
  auto r = __builtin_amdgcn_permlane32_swap(a, b, false, false);
  a = r[0];
  b = r[1];
#else
  unsigned sa = __shfl_xor(a, 32), sb = __shfl_xor(b, 32);
  bool hb = (threadIdx.x & 32) != 0;
  a = hb ? sb : a;
  b = hb ? b : sa;
#endif
}
DEVI void pl32swapf(float& a, float& b) {
  unsigned ua = __builtin_bit_cast(unsigned, a);
  unsigned ub = __builtin_bit_cast(unsigned, b);
  pl32swap(ua, ub);
  a = __builtin_bit_cast(float, ua);
  b = __builtin_bit_cast(float, ub);
}

#define MFMA16(a, b, c) __builtin_amdgcn_mfma_f32_16x16x32_f16((a), (b), (c), 0, 0, 0)
#define MFMA32(a, b, c) __builtin_amdgcn_mfma_f32_32x32x16_f16((a), (b), (c), 0, 0, 0)

// ---- weights -> fp16, FRAG-ORDERED: dst[ot*4096 + ks*512 + g*128 + i*8 + j]
//      = w[oc = 16ot + i][c = 32ks + 8g + j]  (wq pre-scaled by log2e)
__global__ __launch_bounds__(256) void cvt_w(const float* __restrict__ wq,
                                             const float* __restrict__ wk,
                                             const float* __restrict__ wv,
                                             unsigned short* __restrict__ o) {
  int idx = blockIdx.x * 256 + threadIdx.x;     // 3*65536 total
  int mat = idx >> 16, off = idx & 65535;
  const float* s = (mat == 0) ? wq : (mat == 1) ? wk : wv;
  int ot = off >> 12, ks = (off >> 9) & 7, g = (off >> 7) & 3;
  int i = (off >> 3) & 15, j = off & 7;
  float v = s[(ot * 16 + i) * Cn + ks * 32 + g * 8 + j];
  if (mat == 0) v *= 1.44269504f;               // exp2-domain softmax
  o[idx] = f2h(v);
}

// ---------------- QKV projection (z-merged, n-tile 32, frag-ordered w) -----
// grid (N/32, B) = (72, 8), 256 thr = 4 waves. th = w&1 (token half).
__global__ __launch_bounds__(256) void qkv_proj(
    const float* __restrict__ x,
    const unsigned short* __restrict__ wqb, const unsigned short* __restrict__ wkb,
    const unsigned short* __restrict__ wvb,
    unsigned short* __restrict__ Qt, unsigned short* __restrict__ Ksw,
    unsigned short* __restrict__ Vsw) {
  __shared__ unsigned short xT[32][264];        // [token][c], +8 pad
  const int tid = threadIdx.x;
  const int n0 = blockIdx.x * 32;
  const int b = blockIdx.y;
  const float* xb = x + (size_t)b * Cn * Nn;
  {
    int c0 = tid >> 3;
    int nn = (tid & 7) * 4;
#pragma unroll
    for (int it = 0; it < 8; ++it) {
      int c = c0 + 32 * it;
      float4 v = *(const float4*)(xb + (size_t)c * Nn + n0 + nn);
      xT[nn + 0][c] = f2h(v.x);
      xT[nn + 1][c] = f2h(v.y);
      xT[nn + 2][c] = f2h(v.z);
      xT[nn + 3][c] = f2h(v.w);
    }
  }
  __syncthreads();
  const int lane = tid & 63, w = tid >> 6;
  const int i = lane & 15, g = lane >> 4;
  const int th = w & 1;                         // token half (constant both phases)
  const int wlo = g * 128 + i * 8;              // frag-ordered lane offset
  f16x8 xf[8];                                  // x^T frags for tokens th*16..+15
#pragma unroll
  for (int ks = 0; ks < 8; ++ks)
    xf[ks] = *(const f16x8*)(&xT[th * 16 + i][32 * ks + 8 * g]);

  const int kb0 = n0 >> 5;                      // == blockIdx.x (32-token chunk)
  // ---- phase 1: Q (w<2) or K (w>=2), 16 ot-tiles ----
  if (w < 2) {                                  // Q -> token-major [N][C]
    const size_t tokbase = (size_t)b * Nn + n0 + th * 16;
    for (int ot = 0; ot < 16; ++ot) {
      f32x4 acc = {0.f, 0.f, 0.f, 0.f};
      const unsigned short* wr = wqb + ot * 4096 + wlo;
#pragma unroll
      for (int ks = 0; ks < 8; ++ks)
        acc = MFMA16(xf[ks], *(const f16x8*)(wr + 512 * ks), acc);
#pragma unroll
      for (int r = 0; r < 4; ++r)
        Qt[(tokbase + 4 * g + r) * Cn + ot * 16 + i] = f2h(acc[r]);
    }
  } else {                                      // K -> frag-swizzled
    unsigned short* kout = Ksw + (size_t)b * Nn * Cn + (size_t)kb0 * 8192
                         + ((i >> 3) & 1) * 256 + (i & 7);
    const int keyb = th * 16 + 4 * g;           // + r
    for (int ot = 0; ot < 16; ++ot) {
      f32x4 acc = {0.f, 0.f, 0.f, 0.f};
      const unsigned short* wr = wkb + ot * 4096 + wlo;
#pragma unroll
      for (int ks = 0; ks < 8; ++ks)
        acc = MFMA16(xf[ks], *(const f16x8*)(wr + 512 * ks), acc);
#pragma unroll
      for (int r = 0; r < 4; ++r)
        kout[ot * 512 + (keyb + r) * 8] = f2h(acc[r]);
    }
  }
  // ---- phase 2: V, 8 ot-tiles per wave; acc[r]=V[c=ot*16+4g+r][tok=th*16+i]
  {
    unsigned short* vout = Vsw + (size_t)b * Nn * Cn + (size_t)kb0 * 8192
                         + th * 512 + ((i >> 3) & 1) * 256 + (i & 7);
    const int otb = (w >> 1) * 8;
    for (int oo = 0; oo < 8; ++oo) {
      const int ot = otb + oo;
      f32x4 acc = {0.f, 0.f, 0.f, 0.f};
      const unsigned short* wr = wvb + ot * 4096 + wlo;
#pragma unroll
      for (int ks = 0; ks < 8; ++ks)
        acc = MFMA16(*(const f16x8*)(wr + 512 * ks), xf[ks], acc);
#pragma unroll
      for (int r = 0; r < 4; ++r) {
        int c = ot * 16 + 4 * g + r;
        vout[(c >> 5) * 1024 + (c & 31) * 8] = f2h(acc[r]);
      }
    }
  }
}

// ---- flash attention: split-K, K 3-buf LDS, V reg-streamed, T15 x2 --------
// grid Bn*splits*36, 256 thr = 4 waves = 2 q-tiles(32q) x 2 c-halves(128c).
// LDS 48KB = 3 x 16KB K bufs, staged 2-ahead. Mid-iter barrier after explicit
// vmcnt(4). QK^T(t+1) (single chain) overlaps SM(t); dA/dB ping-pong.
__global__ __launch_bounds__(256, 2) void attn_split(
    const unsigned short* __restrict__ Qt, const unsigned short* __restrict__ Ksw,
    const unsigned short* __restrict__ Vsw,
    unsigned short* __restrict__ P, float* __restrict__ ml, int splits) {
  __shared__ unsigned short smem[24576];        // 48 KB
  const int nblk = gridDim.x;                   // divisible by 8
  const int cpx = nblk >> 3;
  const int swz = (blockIdx.x & 7) * cpx + (blockIdx.x >> 3);  // XCD chunked
  const int per_b = splits * 36;
  const int b = swz / per_b;
  const int rem = swz - b * per_b;
  const int s = rem / 36;
  const int qt = rem - s * 36;
  const int n0 = qt * 64;
  const int kn = Nn / splits;
  const int kb0 = (s * kn) >> 5;                // first 32-key chunk id
  const int NT = kn / 32;                       // 18 at splits=4 (even)

  const int tid = threadIdx.x, lane = tid & 63, w = tid >> 6;
  const int q = lane & 31, hi = lane >> 5;
  const int qtile = w & 1, chalf = w >> 1;
  const int q0 = n0 + qtile * 32;

  const unsigned short* Ksrc = Ksw + (size_t)b * Nn * Cn + tid * 8;
  const unsigned short* Vb = Vsw + (size_t)b * Nn * Cn + hi * 256 + q * 8
                           + (size_t)chalf * 4096;

  auto stageK = [&](int kbid, int buf) {        // linear 16KB chunk copy
    unsigned short* dst = smem + buf * 8192 + w * 512;
    const unsigned short* src = Ksrc + (size_t)kbid * 8192;
#pragma unroll
    for (int c4 = 0; c4 < 4; ++c4)
      stage16(src + c4 * 2048, dst + c4 * 2048);
  };

  const int lo = hi * 512 + q * 16;             // byte offset within frag row

  // resident Q B-frags: lane: query=q, c = 16*ks + 8*hi + j
  const unsigned short* Qb = Qt + ((size_t)b * Nn + q0 + q) * Cn + 8 * hi;
  f16x8 qf[16];
#pragma unroll
  for (int ks = 0; ks < 16; ++ks) qf[ks] = *(const f16x8*)(Qb + 16 * ks);

  auto qkt = [&](int buf) -> f32x16 {           // single-chain QK^T
    const char* KsB = (const char*)smem + buf * 16384;
    f32x16 dd = (f32x16)(0.f);
#pragma unroll
    for (int ks = 0; ks < 16; ++ks)
      dd = MFMA32(*(const f16x8*)(KsB + ks * 1024 + lo), qf[ks], dd);
    return dd;
  };

  stageK(kb0, 0);                               // prologue: 2-ahead
  stageK(kb0 + 1, 1);

  f32x16 acc[4];                                // channels chalf*128 .. +128
#pragma unroll
  for (int ct = 0; ct < 4; ++ct) acc[ct] = (f32x16)(0.f);
  float m = -1e30f, lsum = 0.f;                 // lsum: per-half partial

  asm volatile("s_waitcnt vmcnt(4)" ::: "memory");   // own K0 landed (K1 in flight)
  __builtin_amdgcn_sched_barrier(0);
  __builtin_amdgcn_s_barrier();                 // all waves' K0 landed

  auto body = [&](int t, f32x16& dcur, f32x16& dnx) {
    const unsigned short* vp = Vb + (size_t)(kb0 + t) * 8192;
    // ---- V frags for this iter: all 8, issued first ----
    f16x8 vf[8];
#pragma unroll
    for (int ct = 0; ct < 4; ++ct) {
      vf[2 * ct] = *(const f16x8*)(vp + ct * 1024);
      vf[2 * ct + 1] = *(const f16x8*)(vp + ct * 1024 + 512);
    }
    __builtin_amdgcn_sched_barrier(0);          // keep V issues before K stage
    if (t + 2 < NT) stageK(kb0 + t + 2, (t + 2) % 3);

    // vmcnt(4): confirms vf(t) + stageK(t+1) (in-order); leaves stageK(t+2).
    asm volatile("s_waitcnt vmcnt(4)" ::: "memory");
    __builtin_amdgcn_sched_barrier(0);
    __builtin_amdgcn_s_barrier();               // buf(t+1) now block-wide safe

    // ---- QK^T(t+1) on MFMA pipe, overlapped with SM(t) on VALU pipe ----
    if (t + 1 < NT) dnx = qkt((t + 1) % 3);

    // ---- online softmax (log2 domain) on dcur = scores(t) ----
    float u0 = fmaxf(dcur[0], dcur[1]),   u1 = fmaxf(dcur[2], dcur[3]);
    float u2 = fmaxf(dcur[4], dcur[5]),   u3 = fmaxf(dcur[6], dcur[7]);
    float u4 = fmaxf(dcur[8], dcur[9]),   u5 = fmaxf(dcur[10], dcur[11]);
    float u6 = fmaxf(dcur[12], dcur[13]), u7 = fmaxf(dcur[14], dcur[15]);
    float mx = fmaxf(fmaxf(fmaxf(u0, u1), fmaxf(u2, u3)),
                     fmaxf(fmaxf(u4, u5), fmaxf(u6, u7)));
    {                                           // cross-half max (order-robust)
      float mc = mx;
      pl32swapf(mc, mx);
      mx = fmaxf(mc, mx);
    }
    if (__any(mx > m + 12.f)) {                 // defer-max (THR=12 log2)
      float mnew = fmaxf(m, mx);
      float alpha = __builtin_exp2f(m - mnew);
      m = mnew;
      lsum *= alpha;
#pragma unroll
      for (int ct = 0; ct < 4; ++ct)
#pragma unroll
        for (int r = 0; r < 16; ++r) acc[ct][r] *= alpha;
    }
    float p[16];
#pragma unroll
    for (int r = 0; r < 16; ++r) p[r] = __builtin_exp2f(dcur[r] - m);
    float cs = 0.f;
#pragma unroll
    for (int r = 0; r < 16; ++r) cs += p[r];
    lsum += cs;                                 // per-half partial (no shfl)

    // ---- P -> B-frags: swap(A0,A2) yields (pb0.u[0], pb0.u[2]) etc ----
    unsigned A0 = pk2(p[0], p[1]), A1 = pk2(p[2], p[3]);
    unsigned A2 = pk2(p[4], p[5]), A3 = pk2(p[6], p[7]);
    unsigned A4 = pk2(p[8], p[9]), A5 = pk2(p[10], p[11]);
    unsigned A6 = pk2(p[12], p[13]), A7 = pk2(p[14], p[15]);
    pl32swap(A0, A2);
    pl32swap(A1, A3);
    pl32swap(A4, A6);
    pl32swap(A5, A7);
    union { unsigned u[4]; f16x8 v; } pb0, pb1;
    pb0.u[0] = A0; pb0.u[1] = A1; pb0.u[2] = A2; pb0.u[3] = A3;
    pb1.u[0] = A4; pb1.u[1] = A5; pb1.u[2] = A6; pb1.u[3] = A7;

    // ---- PV: 4 c-tiles of this wave's c-half, V from registers ----
    __builtin_amdgcn_s_setprio(1);
    acc[0] = MFMA32(vf[0], pb0.v, acc[0]);
    acc[0] = MFMA32(vf[1], pb1.v, acc[0]);
    acc[1] = MFMA32(vf[2], pb0.v, acc[1]);
    acc[1] = MFMA32(vf[3], pb1.v, acc[1]);
    acc[2] = MFMA32(vf[4], pb0.v, acc[2]);
    acc[2] = MFMA32(vf[5], pb1.v, acc[2]);
    acc[3] = MFMA32(vf[6], pb0.v, acc[3]);
    acc[3] = MFMA32(vf[7], pb1.v, acc[3]);
    __builtin_amdgcn_s_setprio(0);
  };

  f32x16 dA = qkt(0), dB;                       // scores for tile 0
  for (int t = 0; t < NT; t += 2) {             // NT even: no tail
    body(t, dA, dB);
    body(t + 1, dB, dA);
  }

  // ---- epilogue: combine half-sums (order-robust), O_s = acc/lsum ----
  {
    float lc = lsum;
    pl32swapf(lc, lsum);
    lsum += lc;
  }
  const float rl = 1.f / lsum;
  unsigned short* Pb = P + (size_t)(s * Bn + b) * Cn * Nn;
#pragma unroll
  for (int ct = 0; ct < 4; ++ct)
#pragma unroll
    for (int r = 0; r < 16; ++r) {
      int c = 32 * (chalf * 4 + ct) + (r & 3) + 8 * (r >> 2) + 4 * hi;
      Pb[(size_t)c * Nn + q0 + q] = f2h(acc[ct][r] * rl);
    }
  if (!hi && !chalf)
    *(float2*)&ml[((size_t)(s * Bn + b) * Nn + q0 + q) * 2] = make_float2(m, lsum);
}

// ---------------- combine partials + residual (dynamic splits <= 4) --------
// out = x + sum_s w_s * O_s,  w_s = 2^(m_s - M) * l_s / sum(2^(m_s-M) l_s).
__global__ __launch_bounds__(256) void combine_k(
    const float* __restrict__ x, const unsigned short* __restrict__ P,
    const float* __restrict__ ml, float* __restrict__ out, int splits) {
  __shared__ float sc[4][32];
  const int tpb = Nn / 32;                      // 72
  const int b = blockIdx.x / tpb;
  const int n0 = (blockIdx.x - b * tpb) * 32;
  const int t = threadIdx.x;
  if (t < 32) {
    const int n = n0 + t;
    const size_t sstr = (size_t)Bn * Nn * 2;
    const float* mlb = ml + ((size_t)b * Nn + n) * 2;
    float M = -1e30f;
    for (int s2 = 0; s2 < splits; ++s2) M = fmaxf(M, mlb[s2 * sstr]);
    float den = 0.f;
    for (int s2 = 0; s2 < splits; ++s2) {
      float g = __builtin_exp2f(mlb[s2 * sstr] - M) * mlb[s2 * sstr + 1];
      sc[s2][t] = g;
      den += g;
    }
    float rden = 1.f / den;
    for (int s2 = 0; s2 < splits; ++s2) sc[s2][t] *= rden;
  }
  __syncthreads();
  const int nl4 = (t & 7) * 4, c0 = t >> 3;
  const size_t pstr = (size_t)Bn * Cn * Nn;     // shorts per split
  const float* xb = x + (size_t)b * Cn * Nn;
  float* ob = out + (size_t)b * Cn * Nn;
#pragma unroll
  for (int k = 0; k < 8; ++k) {
    const int c = c0 + 32 * k;
    const unsigned short* Pp = P + ((size_t)b * Cn + c) * Nn + n0 + nl4;
    f32x4 a = {0.f, 0.f, 0.f, 0.f};
    for (int s2 = 0; s2 < splits; ++s2) {
      ushort4 ph = *(const ushort4*)(Pp + s2 * pstr);
      f32x4 pv = {h2f(ph.x), h2f(ph.y), h2f(ph.z), h2f(ph.w)};
      f32x4 sw = {sc[s2][nl4 + 0], sc[s2][nl4 + 1], sc[s2][nl4 + 2], sc[s2][nl4 + 3]};
      a += sw * pv;
    }
    f32x4 xv = *(const f32x4*)(xb + (size_t)c * Nn + n0 + nl4);
    *(f32x4*)(ob + (size_t)c * Nn + n0 + nl4) = xv + a;
  }
}

extern "C" void kernel_launch(void* const* d_in, const int* in_sizes, int n_in,
                              void* d_out, int out_size, void* d_ws, size_t ws_size,
                              hipStream_t stream) {
  const float* x = (const float*)d_in[0];
  const float* wq = (const float*)d_in[1];
  const float* wk = (const float*)d_in[2];
  const float* wv = (const float*)d_in[3];
  float* out = (float*)d_out;

  unsigned short* wqb = (unsigned short*)d_ws;
  unsigned short* wkb = wqb + Cn * Cn;
  unsigned short* wvb = wkb + Cn * Cn;
  unsigned short* Qt = wvb + Cn * Cn;
  unsigned short* Ksw = Qt + (size_t)Bn * Nn * Cn;
  unsigned short* Vsw = Ksw + (size_t)Bn * Nn * Cn;
  unsigned short* P = Vsw + (size_t)Bn * Nn * Cn;

  const size_t baseB = (size_t)(3 * Cn * Cn + 3 * (size_t)Bn * Nn * Cn) * 2;
  const size_t perSplitB = (size_t)Bn * Nn * Cn * 2 + (size_t)Bn * Nn * 2 * 4;

  int splits = 1;
  if (baseB + 4 * perSplitB <= ws_size) splits = 4;
  else if (baseB + 2 * perSplitB <= ws_size) splits = 2;

  float* ml = (float*)(P + (size_t)splits * Bn * Nn * Cn);

  hipLaunchKernelGGL(cvt_w, dim3(3 * Cn * Cn / 256), dim3(256), 0, stream, wq, wk, wv, wqb);
  hipLaunchKernelGGL(qkv_proj, dim3(Nn / 32, Bn), dim3(256), 0, stream,
                     x, wqb, wkb, wvb, Qt, Ksw, Vsw);
  hipLaunchKernelGGL(attn_split, dim3(Bn * splits * 36), dim3(256), 0, stream,
                     Qt, Ksw, Vsw, P, ml, splits);
  hipLaunchKernelGGL(combine_k, dim3(Bn * Nn / 32), dim3(256), 0, stream,
                     x, P, ml, out, splits);
}

// Round 21
// 160.413 us; speedup vs baseline: 1.0843x; 1.0278x over previous
//
#include <hip/hip_runtime.h>
#include <hip/hip_bf16.h>

// SelfAttention: x[8,256,48,48] fp32; wq/wk/wv[256,256] fp32.
// out = x + attn(softmax(q^T k), v). B=8, C=256, N=2304. fp16 MFMA path.
//
// R20 post-mortem: revert confirmed (164.9us ~ R18 best). Audit found the
// per-iter vmcnt(4) OVER-WAITS: publishing buf(t+1) only needs st(t+1)
// retired = vmcnt(12) (queue: [st(t+1)4, vf(t)8, st(t+2)4]); vmcnt(4) also
// forced vf(t) retirement -> ~100-200cy V-latency stall on the critical path
// every iter. R21: counted wait vmcnt(12) (vmcnt(8) for t+2>=NT where no
// stage was issued). Single change vs R20.
//
// K_swz[kb][ks 16][hi 2][key 32][j 8]: short off = kb*8192+ks*512+hi*256+key*8+j
// V_swz[kb][ct 8][kh 2][hi 2][c 32][j 8]: off = kb*8192+ct*1024+kh*512+hi*256+c*8+j
// weights frag-ordered: off = ot*4096 + ks*512 + g*128 + i*8 + j
// ws: wq/wk/wv fp16 [65536 ea]; Qt [B*N*C] token-major; Ksw,Vsw [B*N*C];
//     P fp16 [splits][B][C][N]; ml f32 [splits][B][N][2].

#define DEVI __device__ __forceinline__

typedef _Float16 f16x8 __attribute__((ext_vector_type(8)));
typedef float f32x4 __attribute__((ext_vector_type(4)));
typedef float f32x16 __attribute__((ext_vector_type(16)));

constexpr int Bn = 8, Cn = 256, Nn = 48 * 48;   // 2304

#if defined(__has_builtin)
#if __has_builtin(__builtin_amdgcn_permlane32_swap)
#define HAVE_PL32 1
#endif
#endif

DEVI unsigned short f2h(float f) {
  _Float16 h = (_Float16)f;
  return __builtin_bit_cast(unsigned short, h);
}
DEVI float h2f(unsigned short u) {
  return (float)__builtin_bit_cast(_Float16, u);
}
DEVI unsigned pk2(float a, float b) {           // pack 2 f32 -> f16x2 (RTZ)
  auto h = __builtin_amdgcn_cvt_pkrtz(a, b);
  return __builtin_bit_cast(unsigned, h);
}
DEVI void stage16(const unsigned short* g, unsigned short* l) {
  __builtin_amdgcn_global_load_lds(
      (const __attribute__((address_space(1))) void*)g,
      (__attribute__((address_space(3))) void*)l, 16, 0, 0);
}
// permlane32_swap(a,b): a' = {a.lo, b.lo}; b' = {a.hi, b.hi}
DEVI void pl32swap(unsigned& a, unsigned& b) {
#ifdef HAVE_PL32
  auto r = __builtin_amdgcn_permlane32_swap(a, b, false, false);
  a = r[0];
  b = r[1];
#else
  unsigned sa = __shfl_xor(a, 32), sb = __shfl_xor(b, 32);
  bool hb = (threadIdx.x & 32) != 0;
  a = hb ? sb : a;
  b = hb ? b : sa;
#endif
}
DEVI void pl32swapf(float& a, float& b) {
  unsigned ua = __builtin_bit_cast(unsigned, a);
  unsigned ub = __builtin_bit_cast(unsigned, b);
  pl32swap(ua, ub);
  a = __builtin_bit_cast(float, ua);
  b = __builtin_bit_cast(float, ub);
}

#define MFMA16(a, b, c) __builtin_amdgcn_mfma_f32_16x16x32_f16((a), (b), (c), 0, 0, 0)
#define MFMA32(a, b, c) __builtin_amdgcn_mfma_f32_32x32x16_f16((a), (b), (c), 0, 0, 0)

// ---- weights -> fp16, FRAG-ORDERED: dst[ot*4096 + ks*512 + g*128 + i*8 + j]
//      = w[oc = 16ot + i][c = 32ks + 8g + j]  (wq pre-scaled by log2e)
__global__ __launch_bounds__(256) void cvt_w(const float* __restrict__ wq,
                                             const float* __restrict__ wk,
                                             const float* __restrict__ wv,
                                             unsigned short* __restrict__ o) {
  int idx = blockIdx.x * 256 + threadIdx.x;     // 3*65536 total
  int mat = idx >> 16, off = idx & 65535;
  const float* s = (mat == 0) ? wq : (mat == 1) ? wk : wv;
  int ot = off >> 12, ks = (off >> 9) & 7, g = (off >> 7) & 3;
  int i = (off >> 3) & 15, j = off & 7;
  float v = s[(ot * 16 + i) * Cn + ks * 32 + g * 8 + j];
  if (mat == 0) v *= 1.44269504f;               // exp2-domain softmax
  o[idx] = f2h(v);
}

// ---------------- QKV projection (z-merged, n-tile 32, frag-ordered w) -----
// grid (N/32, B) = (72, 8), 256 thr = 4 waves. th = w&1 (token half).
__global__ __launch_bounds__(256) void qkv_proj(
    const float* __restrict__ x,
    const unsigned short* __restrict__ wqb, const unsigned short* __restrict__ wkb,
    const unsigned short* __restrict__ wvb,
    unsigned short* __restrict__ Qt, unsigned short* __restrict__ Ksw,
    unsigned short* __restrict__ Vsw) {
  __shared__ unsigned short xT[32][264];        // [token][c], +8 pad
  const int tid = threadIdx.x;
  const int n0 = blockIdx.x * 32;
  const int b = blockIdx.y;
  const float* xb = x + (size_t)b * Cn * Nn;
  {
    int c0 = tid >> 3;
    int nn = (tid & 7) * 4;
#pragma unroll
    for (int it = 0; it < 8; ++it) {
      int c = c0 + 32 * it;
      float4 v = *(const float4*)(xb + (size_t)c * Nn + n0 + nn);
      xT[nn + 0][c] = f2h(v.x);
      xT[nn + 1][c] = f2h(v.y);
      xT[nn + 2][c] = f2h(v.z);
      xT[nn + 3][c] = f2h(v.w);
    }
  }
  __syncthreads();
  const int lane = tid & 63, w = tid >> 6;
  const int i = lane & 15, g = lane >> 4;
  const int th = w & 1;                         // token half (constant both phases)
  const int wlo = g * 128 + i * 8;              // frag-ordered lane offset
  f16x8 xf[8];                                  // x^T frags for tokens th*16..+15
#pragma unroll
  for (int ks = 0; ks < 8; ++ks)
    xf[ks] = *(const f16x8*)(&xT[th * 16 + i][32 * ks + 8 * g]);

  const int kb0 = n0 >> 5;                      // == blockIdx.x (32-token chunk)
  // ---- phase 1: Q (w<2) or K (w>=2), 16 ot-tiles ----
  if (w < 2) {                                  // Q -> token-major [N][C]
    const size_t tokbase = (size_t)b * Nn + n0 + th * 16;
    for (int ot = 0; ot < 16; ++ot) {
      f32x4 acc = {0.f, 0.f, 0.f, 0.f};
      const unsigned short* wr = wqb + ot * 4096 + wlo;
#pragma unroll
      for (int ks = 0; ks < 8; ++ks)
        acc = MFMA16(xf[ks], *(const f16x8*)(wr + 512 * ks), acc);
#pragma unroll
      for (int r = 0; r < 4; ++r)
        Qt[(tokbase + 4 * g + r) * Cn + ot * 16 + i] = f2h(acc[r]);
    }
  } else {                                      // K -> frag-swizzled
    unsigned short* kout = Ksw + (size_t)b * Nn * Cn + (size_t)kb0 * 8192
                         + ((i >> 3) & 1) * 256 + (i & 7);
    const int keyb = th * 16 + 4 * g;           // + r
    for (int ot = 0; ot < 16; ++ot) {
      f32x4 acc = {0.f, 0.f, 0.f, 0.f};
      const unsigned short* wr = wkb + ot * 4096 + wlo;
#pragma unroll
      for (int ks = 0; ks < 8; ++ks)
        acc = MFMA16(xf[ks], *(const f16x8*)(wr + 512 * ks), acc);
#pragma unroll
      for (int r = 0; r < 4; ++r)
        kout[ot * 512 + (keyb + r) * 8] = f2h(acc[r]);
    }
  }
  // ---- phase 2: V, 8 ot-tiles per wave; acc[r]=V[c=ot*16+4g+r][tok=th*16+i]
  {
    unsigned short* vout = Vsw + (size_t)b * Nn * Cn + (size_t)kb0 * 8192
                         + th * 512 + ((i >> 3) & 1) * 256 + (i & 7);
    const int otb = (w >> 1) * 8;
    for (int oo = 0; oo < 8; ++oo) {
      const int ot = otb + oo;
      f32x4 acc = {0.f, 0.f, 0.f, 0.f};
      const unsigned short* wr = wvb + ot * 4096 + wlo;
#pragma unroll
      for (int ks = 0; ks < 8; ++ks)
        acc = MFMA16(*(const f16x8*)(wr + 512 * ks), xf[ks], acc);
#pragma unroll
      for (int r = 0; r < 4; ++r) {
        int c = ot * 16 + 4 * g + r;
        vout[(c >> 5) * 1024 + (c & 31) * 8] = f2h(acc[r]);
      }
    }
  }
}

// ---- flash attention: split-K, K 3-buf LDS, V reg-streamed, T15 x2 --------
// grid Bn*splits*36, 256 thr = 4 waves = 2 q-tiles(32q) x 2 c-halves(128c).
// LDS 48KB = 3 x 16KB K bufs, staged 2-ahead. Mid-iter barrier after COUNTED
// vmcnt(12): publishes st(t+1) without draining vf(t) (V waits at PV only).
__global__ __launch_bounds__(256, 2) void attn_split(
    const unsigned short* __restrict__ Qt, const unsigned short* __restrict__ Ksw,
    const unsigned short* __restrict__ Vsw,
    unsigned short* __restrict__ P, float* __restrict__ ml, int splits) {
  __shared__ unsigned short smem[24576];        // 48 KB
  const int nblk = gridDim.x;                   // divisible by 8
  const int cpx = nblk >> 3;
  const int swz = (blockIdx.x & 7) * cpx + (blockIdx.x >> 3);  // XCD chunked
  const int per_b = splits * 36;
  const int b = swz / per_b;
  const int rem = swz - b * per_b;
  const int s = rem / 36;
  const int qt = rem - s * 36;
  const int n0 = qt * 64;
  const int kn = Nn / splits;
  const int kb0 = (s * kn) >> 5;                // first 32-key chunk id
  const int NT = kn / 32;                       // 18 at splits=4 (even)

  const int tid = threadIdx.x, lane = tid & 63, w = tid >> 6;
  const int q = lane & 31, hi = lane >> 5;
  const int qtile = w & 1, chalf = w >> 1;
  const int q0 = n0 + qtile * 32;

  const unsigned short* Ksrc = Ksw + (size_t)b * Nn * Cn + tid * 8;
  const unsigned short* Vb = Vsw + (size_t)b * Nn * Cn + hi * 256 + q * 8
                           + (size_t)chalf * 4096;

  auto stageK = [&](int kbid, int buf) {        // linear 16KB chunk copy
    unsigned short* dst = smem + buf * 8192 + w * 512;
    const unsigned short* src = Ksrc + (size_t)kbid * 8192;
#pragma unroll
    for (int c4 = 0; c4 < 4; ++c4)
      stage16(src + c4 * 2048, dst + c4 * 2048);
  };

  const int lo = hi * 512 + q * 16;             // byte offset within frag row

  // resident Q B-frags: lane: query=q, c = 16*ks + 8*hi + j
  const unsigned short* Qb = Qt + ((size_t)b * Nn + q0 + q) * Cn + 8 * hi;
  f16x8 qf[16];
#pragma unroll
  for (int ks = 0; ks < 16; ++ks) qf[ks] = *(const f16x8*)(Qb + 16 * ks);

  auto qkt = [&](int buf) -> f32x16 {           // single-chain QK^T
    const char* KsB = (const char*)smem + buf * 16384;
    f32x16 dd = (f32x16)(0.f);
#pragma unroll
    for (int ks = 0; ks < 16; ++ks)
      dd = MFMA32(*(const f16x8*)(KsB + ks * 1024 + lo), qf[ks], dd);
    return dd;
  };

  stageK(kb0, 0);                               // prologue: 2-ahead
  stageK(kb0 + 1, 1);

  f32x16 acc[4];                                // channels chalf*128 .. +128
#pragma unroll
  for (int ct = 0; ct < 4; ++ct) acc[ct] = (f32x16)(0.f);
  float m = -1e30f, lsum = 0.f;                 // lsum: per-half partial

  asm volatile("s_waitcnt vmcnt(4)" ::: "memory");   // own K0 landed (K1 in flight)
  __builtin_amdgcn_sched_barrier(0);
  __builtin_amdgcn_s_barrier();                 // all waves' K0 landed

  auto body = [&](int t, f32x16& dcur, f32x16& dnx) {
    const unsigned short* vp = Vb + (size_t)(kb0 + t) * 8192;
    // ---- V frags for this iter: all 8, issued first ----
    f16x8 vf[8];
#pragma unroll
    for (int ct = 0; ct < 4; ++ct) {
      vf[2 * ct] = *(const f16x8*)(vp + ct * 1024);
      vf[2 * ct + 1] = *(const f16x8*)(vp + ct * 1024 + 512);
    }
    __builtin_amdgcn_sched_barrier(0);          // keep V issues before K stage
    if (t + 2 < NT) stageK(kb0 + t + 2, (t + 2) % 3);

    // Counted wait: queue = [st(t+1) 4, vf(t) 8, st(t+2) 4]. Publishing
    // buf(t+1) needs only st(t+1) retired -> vmcnt(12); vf(t) stays in
    // flight (compiler waits it at PV). No stage issued when t+2>=NT ->
    // queue = [st(t+1) 4, vf(t) 8] -> vmcnt(8) to still retire st(t+1).
    if (t + 2 < NT)
      asm volatile("s_waitcnt vmcnt(12)" ::: "memory");
    else
      asm volatile("s_waitcnt vmcnt(8)" ::: "memory");
    __builtin_amdgcn_sched_barrier(0);
    __builtin_amdgcn_s_barrier();               // buf(t+1) now block-wide safe

    // ---- QK^T(t+1) on MFMA pipe, overlapped with SM(t) on VALU pipe ----
    if (t + 1 < NT) dnx = qkt((t + 1) % 3);

    // ---- online softmax (log2 domain) on dcur = scores(t) ----
    float u0 = fmaxf(dcur[0], dcur[1]),   u1 = fmaxf(dcur[2], dcur[3]);
    float u2 = fmaxf(dcur[4], dcur[5]),   u3 = fmaxf(dcur[6], dcur[7]);
    float u4 = fmaxf(dcur[8], dcur[9]),   u5 = fmaxf(dcur[10], dcur[11]);
    float u6 = fmaxf(dcur[12], dcur[13]), u7 = fmaxf(dcur[14], dcur[15]);
    float mx = fmaxf(fmaxf(fmaxf(u0, u1), fmaxf(u2, u3)),
                     fmaxf(fmaxf(u4, u5), fmaxf(u6, u7)));
    {                                           // cross-half max (order-robust)
      float mc = mx;
      pl32swapf(mc, mx);
      mx = fmaxf(mc, mx);
    }
    if (__any(mx > m + 12.f)) {                 // defer-max (THR=12 log2)
      float mnew = fmaxf(m, mx);
      float alpha = __builtin_exp2f(m - mnew);
      m = mnew;
      lsum *= alpha;
#pragma unroll
      for (int ct = 0; ct < 4; ++ct)
#pragma unroll
        for (int r = 0; r < 16; ++r) acc[ct][r] *= alpha;
    }
    float p[16];
#pragma unroll
    for (int r = 0; r < 16; ++r) p[r] = __builtin_exp2f(dcur[r] - m);
    float cs = 0.f;
#pragma unroll
    for (int r = 0; r < 16; ++r) cs += p[r];
    lsum += cs;                                 // per-half partial (no shfl)

    // ---- P -> B-frags: swap(A0,A2) yields (pb0.u[0], pb0.u[2]) etc ----
    unsigned A0 = pk2(p[0], p[1]), A1 = pk2(p[2], p[3]);
    unsigned A2 = pk2(p[4], p[5]), A3 = pk2(p[6], p[7]);
    unsigned A4 = pk2(p[8], p[9]), A5 = pk2(p[10], p[11]);
    unsigned A6 = pk2(p[12], p[13]), A7 = pk2(p[14], p[15]);
    pl32swap(A0, A2);
    pl32swap(A1, A3);
    pl32swap(A4, A6);
    pl32swap(A5, A7);
    union { unsigned u[4]; f16x8 v; } pb0, pb1;
    pb0.u[0] = A0; pb0.u[1] = A1; pb0.u[2] = A2; pb0.u[3] = A3;
    pb1.u[0] = A4; pb1.u[1] = A5; pb1.u[2] = A6; pb1.u[3] = A7;

    // ---- PV: 4 c-tiles of this wave's c-half, V from registers ----
    __builtin_amdgcn_s_setprio(1);
    acc[0] = MFMA32(vf[0], pb0.v, acc[0]);
    acc[0] = MFMA32(vf[1], pb1.v, acc[0]);
    acc[1] = MFMA32(vf[2], pb0.v, acc[1]);
    acc[1] = MFMA32(vf[3], pb1.v, acc[1]);
    acc[2] = MFMA32(vf[4], pb0.v, acc[2]);
    acc[2] = MFMA32(vf[5], pb1.v, acc[2]);
    acc[3] = MFMA32(vf[6], pb0.v, acc[3]);
    acc[3] = MFMA32(vf[7], pb1.v, acc[3]);
    __builtin_amdgcn_s_setprio(0);
  };

  f32x16 dA = qkt(0), dB;                       // scores for tile 0
  for (int t = 0; t < NT; t += 2) {             // NT even: no tail
    body(t, dA, dB);
    body(t + 1, dB, dA);
  }

  // ---- epilogue: combine half-sums (order-robust), O_s = acc/lsum ----
  {
    float lc = lsum;
    pl32swapf(lc, lsum);
    lsum += lc;
  }
  const float rl = 1.f / lsum;
  unsigned short* Pb = P + (size_t)(s * Bn + b) * Cn * Nn;
#pragma unroll
  for (int ct = 0; ct < 4; ++ct)
#pragma unroll
    for (int r = 0; r < 16; ++r) {
      int c = 32 * (chalf * 4 + ct) + (r & 3) + 8 * (r >> 2) + 4 * hi;
      Pb[(size_t)c * Nn + q0 + q] = f2h(acc[ct][r] * rl);
    }
  if (!hi && !chalf)
    *(float2*)&ml[((size_t)(s * Bn + b) * Nn + q0 + q) * 2] = make_float2(m, lsum);
}

// ---------------- combine partials + residual (dynamic splits <= 4) --------
// out = x + sum_s w_s * O_s,  w_s = 2^(m_s - M) * l_s / sum(2^(m_s-M) l_s).
__global__ __launch_bounds__(256) void combine_k(
    const float* __restrict__ x, const unsigned short* __restrict__ P,
    const float* __restrict__ ml, float* __restrict__ out, int splits) {
  __shared__ float sc[4][32];
  const int tpb = Nn / 32;                      // 72
  const int b = blockIdx.x / tpb;
  const int n0 = (blockIdx.x - b * tpb) * 32;
  const int t = threadIdx.x;
  if (t < 32) {
    const int n = n0 + t;
    const size_t sstr = (size_t)Bn * Nn * 2;
    const float* mlb = ml + ((size_t)b * Nn + n) * 2;
    float M = -1e30f;
    for (int s2 = 0; s2 < splits; ++s2) M = fmaxf(M, mlb[s2 * sstr]);
    float den = 0.f;
    for (int s2 = 0; s2 < splits; ++s2) {
      float g = __builtin_exp2f(mlb[s2 * sstr] - M) * mlb[s2 * sstr + 1];
      sc[s2][t] = g;
      den += g;
    }
    float rden = 1.f / den;
    for (int s2 = 0; s2 < splits; ++s2) sc[s2][t] *= rden;
  }
  __syncthreads();
  const int nl4 = (t & 7) * 4, c0 = t >> 3;
  const size_t pstr = (size_t)Bn * Cn * Nn;     // shorts per split
  const float* xb = x + (size_t)b * Cn * Nn;
  float* ob = out + (size_t)b * Cn * Nn;
#pragma unroll
  for (int k = 0; k < 8; ++k) {
    const int c = c0 + 32 * k;
    const unsigned short* Pp = P + ((size_t)b * Cn + c) * Nn + n0 + nl4;
    f32x4 a = {0.f, 0.f, 0.f, 0.f};
    for (int s2 = 0; s2 < splits; ++s2) {
      ushort4 ph = *(const ushort4*)(Pp + s2 * pstr);
      f32x4 pv = {h2f(ph.x), h2f(ph.y), h2f(ph.z), h2f(ph.w)};
      f32x4 sw = {sc[s2][nl4 + 0], sc[s2][nl4 + 1], sc[s2][nl4 + 2], sc[s2][nl4 + 3]};
      a += sw * pv;
    }
    f32x4 xv = *(const f32x4*)(xb + (size_t)c * Nn + n0 + nl4);
    *(f32x4*)(ob + (size_t)c * Nn + n0 + nl4) = xv + a;
  }
}

extern "C" void kernel_launch(void* const* d_in, const int* in_sizes, int n_in,
                              void* d_out, int out_size, void* d_ws, size_t ws_size,
                              hipStream_t stream) {
  const float* x = (const float*)d_in[0];
  const float* wq = (const float*)d_in[1];
  const float* wk = (const float*)d_in[2];
  const float* wv = (const float*)d_in[3];
  float* out = (float*)d_out;

  unsigned short* wqb = (unsigned short*)d_ws;
  unsigned short* wkb = wqb + Cn * Cn;
  unsigned short* wvb = wkb + Cn * Cn;
  unsigned short* Qt = wvb + Cn * Cn;
  unsigned short* Ksw = Qt + (size_t)Bn * Nn * Cn;
  unsigned short* Vsw = Ksw + (size_t)Bn * Nn * Cn;
  unsigned short* P = Vsw + (size_t)Bn * Nn * Cn;

  const size_t baseB = (size_t)(3 * Cn * Cn + 3 * (size_t)Bn * Nn * Cn) * 2;
  const size_t perSplitB = (size_t)Bn * Nn * Cn * 2 + (size_t)Bn * Nn * 2 * 4;

  int splits = 1;
  if (baseB + 4 * perSplitB <= ws_size) splits = 4;
  else if (baseB + 2 * perSplitB <= ws_size) splits = 2;

  float* ml = (float*)(P + (size_t)splits * Bn * Nn * Cn);

  hipLaunchKernelGGL(cvt_w, dim3(3 * Cn * Cn / 256), dim3(256), 0, stream, wq, wk, wv, wqb);
  hipLaunchKernelGGL(qkv_proj, dim3(Nn / 32, Bn), dim3(256), 0, stream,
                     x, wqb, wkb, wvb, Qt, Ksw, Vsw);
  hipLaunchKernelGGL(attn_split, dim3(Bn * splits * 36), dim3(256), 0, stream,
                     Qt, Ksw, Vsw, P, ml, splits);
  hipLaunchKernelGGL(combine_k, dim3(Bn * Nn / 32), dim3(256), 0, stream,
                     x, P, ml, out, splits);
}

// Round 23
// 149.369 us; speedup vs baseline: 1.1644x; 1.0739x over previous
//
#include <hip/hip_runtime.h>
#include <hip/hip_bf16.h>

// SelfAttention: x[8,256,48,48] fp32; wq/wk/wv[256,256] fp32.
// out = x + attn(softmax(q^T k), v). B=8, C=256, N=2304. fp16 MFMA path.
//
// R22 post-mortem: NaN — weight tile is 4096 SHORTS (8KB, ks*512 for ks<8),
// but wbuf tile was sized/staged as 2048 -> compute read past staged data.
// R23: corrected LDS weight staging: 2-deep ring of 2x8KB tiles (32KB),
// stage AFTER the step barrier (write-after-read separated: all waves
// finished compute(e-1) before any wave passes barrier(e)), plain
// __syncthreads per step (implicit vmcnt(0) publishes st(e)). Each tile
// staged once per block: weight L2 traffic 442->221 MB. Compute bodies
// bit-identical. attn_split/cvt_w/combine_k = R21 exactly (160.4us PASS).
//
// K_swz[kb][ks 16][hi 2][key 32][j 8]: short off = kb*8192+ks*512+hi*256+key*8+j
// V_swz[kb][ct 8][kh 2][hi 2][c 32][j 8]: off = kb*8192+ct*1024+kh*512+hi*256+c*8+j
// weights frag-ordered: off = ot*4096 + ks*512 + g*128 + i*8 + j
// ws: wq/wk/wv fp16 [65536 ea]; Qt [B*N*C] token-major; Ksw,Vsw [B*N*C];
//     P fp16 [splits][B][C][N]; ml f32 [splits][B][N][2].

#define DEVI __device__ __forceinline__

typedef _Float16 f16x8 __attribute__((ext_vector_type(8)));
typedef float f32x4 __attribute__((ext_vector_type(4)));
typedef float f32x16 __attribute__((ext_vector_type(16)));

constexpr int Bn = 8, Cn = 256, Nn = 48 * 48;   // 2304

#if defined(__has_builtin)
#if __has_builtin(__builtin_amdgcn_permlane32_swap)
#define HAVE_PL32 1
#endif
#endif

DEVI unsigned short f2h(float f) {
  _Float16 h = (_Float16)f;
  return __builtin_bit_cast(unsigned short, h);
}
DEVI float h2f(unsigned short u) {
  return (float)__builtin_bit_cast(_Float16, u);
}
DEVI unsigned pk2(float a, float b) {           // pack 2 f32 -> f16x2 (RTZ)
  auto h = __builtin_amdgcn_cvt_pkrtz(a, b);
  return __builtin_bit_cast(unsigned, h);
}
DEVI void stage16(const unsigned short* g, unsigned short* l) {
  __builtin_amdgcn_global_load_lds(
      (const __attribute__((address_space(1))) void*)g,
      (__attribute__((address_space(3))) void*)l, 16, 0, 0);
}
// permlane32_swap(a,b): a' = {a.lo, b.lo}; b' = {a.hi, b.hi}
DEVI void pl32swap(unsigned& a, unsigned& b) {
#ifdef HAVE_PL32
  auto r = __builtin_amdgcn_permlane32_swap(a, b, false, false);
  a = r[0];
  b = r[1];
#else
  unsigned sa = __shfl_xor(a, 32), sb = __shfl_xor(b, 32);
  bool hb = (threadIdx.x & 32) != 0;
  a = hb ? sb : a;
  b = hb ? b : sa;
#endif
}
DEVI void pl32swapf(float& a, float& b) {
  unsigned ua = __builtin_bit_cast(unsigned, a);
  unsigned ub = __builtin_bit_cast(unsigned, b);
  pl32swap(ua, ub);
  a = __builtin_bit_cast(float, ua);
  b = __builtin_bit_cast(float, ub);
}

#define MFMA16(a, b, c) __builtin_amdgcn_mfma_f32_16x16x32_f16((a), (b), (c), 0, 0, 0)
#define MFMA32(a, b, c) __builtin_amdgcn_mfma_f32_32x32x16_f16((a), (b), (c), 0, 0, 0)

// ---- weights -> fp16, FRAG-ORDERED: dst[ot*4096 + ks*512 + g*128 + i*8 + j]
//      = w[oc = 16ot + i][c = 32ks + 8g + j]  (wq pre-scaled by log2e)
__global__ __launch_bounds__(256) void cvt_w(const float* __restrict__ wq,
                                             const float* __restrict__ wk,
                                             const float* __restrict__ wv,
                                             unsigned short* __restrict__ o) {
  int idx = blockIdx.x * 256 + threadIdx.x;     // 3*65536 total
  int mat = idx >> 16, off = idx & 65535;
  const float* s = (mat == 0) ? wq : (mat == 1) ? wk : wv;
  int ot = off >> 12, ks = (off >> 9) & 7, g = (off >> 7) & 3;
  int i = (off >> 3) & 15, j = off & 7;
  float v = s[(ot * 16 + i) * Cn + ks * 32 + g * 8 + j];
  if (mat == 0) v *= 1.44269504f;               // exp2-domain softmax
  o[idx] = f2h(v);
}

// ---------------- QKV projection (LDS-staged weights, n-tile 32) -----------
// grid (N/32, B) = (72, 8), 256 thr = 4 waves. th = w&1 (token half).
// 24 steps: e<16: {wq[e], wk[e]}: w0,w1 -> Q[e] th0,1; w2,w3 -> K[e] th0,1.
//           e>=16: {wv[2(e-16)], wv[2(e-16)+1]}: wave pair (w>>1) per tile.
// 8KB tiles staged once per block into 2-deep ring (32KB); stage AFTER the
// step __syncthreads (implicit vmcnt(0) publishes st(e); barrier separates
// compute(e-1) reads from st(e+1) writes).
__global__ __launch_bounds__(256) void qkv_proj(
    const float* __restrict__ x,
    const unsigned short* __restrict__ wqb, const unsigned short* __restrict__ wkb,
    const unsigned short* __restrict__ wvb,
    unsigned short* __restrict__ Qt, unsigned short* __restrict__ Ksw,
    unsigned short* __restrict__ Vsw) {
  __shared__ unsigned short xT[32][264];        // [token][c], +8 pad (16.9 KB)
  __shared__ unsigned short wbuf[2][2][4096];   // 2 bufs x 2 tiles x 8KB (32 KB)
  const int tid = threadIdx.x;
  const int n0 = blockIdx.x * 32;
  const int b = blockIdx.y;
  const float* xb = x + (size_t)b * Cn * Nn;
  {
    int c0 = tid >> 3;
    int nn = (tid & 7) * 4;
#pragma unroll
    for (int it = 0; it < 8; ++it) {
      int c = c0 + 32 * it;
      float4 v = *(const float4*)(xb + (size_t)c * Nn + n0 + nn);
      xT[nn + 0][c] = f2h(v.x);
      xT[nn + 1][c] = f2h(v.y);
      xT[nn + 2][c] = f2h(v.z);
      xT[nn + 3][c] = f2h(v.w);
    }
  }
  const int lane = tid & 63, w = tid >> 6;
  const int i = lane & 15, g = lane >> 4;
  const int th = w & 1;                         // token half
  const int wlo = g * 128 + i * 8;              // frag-ordered lane offset

  // stage step e into buf: 2 tiles x 8KB; wave w covers shorts [w*1024,+1024)
  // of each tile via 2 stage16 (each = 64 lanes x 16B = 512 shorts).
  auto stageW = [&](int e, int buf) {
    const unsigned short* s0;
    const unsigned short* s1;
    if (e < 16) {
      s0 = wqb + e * 4096;
      s1 = wkb + e * 4096;
    } else {
      int ee = e - 16;
      s0 = wvb + (2 * ee) * 4096;
      s1 = wvb + (2 * ee + 1) * 4096;
    }
    stage16(s0 + w * 1024 + lane * 8,       &wbuf[buf][0][w * 1024]);
    stage16(s0 + w * 1024 + 512 + lane * 8, &wbuf[buf][0][w * 1024 + 512]);
    stage16(s1 + w * 1024 + lane * 8,       &wbuf[buf][1][w * 1024]);
    stage16(s1 + w * 1024 + 512 + lane * 8, &wbuf[buf][1][w * 1024 + 512]);
  };

  stageW(0, 0);                                 // prologue
  __syncthreads();                              // drains xT writes + st(0)

  f16x8 xf[8];                                  // x^T frags for tokens th*16..+15
#pragma unroll
  for (int ks = 0; ks < 8; ++ks)
    xf[ks] = *(const f16x8*)(&xT[th * 16 + i][32 * ks + 8 * g]);

  const int kb0 = n0 >> 5;                      // == blockIdx.x (32-token chunk)
  const size_t tokbase = (size_t)b * Nn + n0 + th * 16;
  unsigned short* kout = Ksw + (size_t)b * Nn * Cn + (size_t)kb0 * 8192
                       + ((i >> 3) & 1) * 256 + (i & 7);
  const int keyb = th * 16 + 4 * g;
  unsigned short* vout = Vsw + (size_t)b * Nn * Cn + (size_t)kb0 * 8192
                       + th * 512 + ((i >> 3) & 1) * 256 + (i & 7);

  for (int e = 0; e < 24; ++e) {
    if (e) __syncthreads();                     // vmcnt(0): st(e) published;
                                                // all waves done compute(e-1)
    if (e + 1 < 24) stageW(e + 1, (e + 1) & 1); // safe: slot's readers done

    const unsigned short* wr = &wbuf[e & 1][w >> 1][wlo];
    if (e < 16) {                               // phase 1: Q (w<2) / K (w>=2)
      const int ot = e;
      f32x4 acc = {0.f, 0.f, 0.f, 0.f};
#pragma unroll
      for (int ks = 0; ks < 8; ++ks)
        acc = MFMA16(xf[ks], *(const f16x8*)(wr + 512 * ks), acc);
      if (w < 2) {
#pragma unroll
        for (int r = 0; r < 4; ++r)
          Qt[(tokbase + 4 * g + r) * Cn + ot * 16 + i] = f2h(acc[r]);
      } else {
#pragma unroll
        for (int r = 0; r < 4; ++r)
          kout[ot * 512 + (keyb + r) * 8] = f2h(acc[r]);
      }
    } else {                                    // phase 2: V
      const int ot = 2 * (e - 16) + (w >> 1);
      f32x4 acc = {0.f, 0.f, 0.f, 0.f};
#pragma unroll
      for (int ks = 0; ks < 8; ++ks)
        acc = MFMA16(*(const f16x8*)(wr + 512 * ks), xf[ks], acc);
#pragma unroll
      for (int r = 0; r < 4; ++r) {
        int c = ot * 16 + 4 * g + r;
        vout[(c >> 5) * 1024 + (c & 31) * 8] = f2h(acc[r]);
      }
    }
  }
}

// ---- flash attention: split-K, K 3-buf LDS, V reg-streamed, T15 x2 --------
// grid Bn*splits*36, 256 thr = 4 waves = 2 q-tiles(32q) x 2 c-halves(128c).
// LDS 48KB = 3 x 16KB K bufs, staged 2-ahead. Mid-iter barrier after COUNTED
// vmcnt(12): publishes st(t+1) without draining vf(t) (V waits at PV only).
__global__ __launch_bounds__(256, 2) void attn_split(
    const unsigned short* __restrict__ Qt, const unsigned short* __restrict__ Ksw,
    const unsigned short* __restrict__ Vsw,
    unsigned short* __restrict__ P, float* __restrict__ ml, int splits) {
  __shared__ unsigned short smem[24576];        // 48 KB
  const int nblk = gridDim.x;                   // divisible by 8
  const int cpx = nblk >> 3;
  const int swz = (blockIdx.x & 7) * cpx + (blockIdx.x >> 3);  // XCD chunked
  const int per_b = splits * 36;
  const int b = swz / per_b;
  const int rem = swz - b * per_b;
  const int s = rem / 36;
  const int qt = rem - s * 36;
  const int n0 = qt * 64;
  const int kn = Nn / splits;
  const int kb0 = (s * kn) >> 5;                // first 32-key chunk id
  const int NT = kn / 32;                       // 18 at splits=4 (even)

  const int tid = threadIdx.x, lane = tid & 63, w = tid >> 6;
  const int q = lane & 31, hi = lane >> 5;
  const int qtile = w & 1, chalf = w >> 1;
  const int q0 = n0 + qtile * 32;

  const unsigned short* Ksrc = Ksw + (size_t)b * Nn * Cn + tid * 8;
  const unsigned short* Vb = Vsw + (size_t)b * Nn * Cn + hi * 256 + q * 8
                           + (size_t)chalf * 4096;

  auto stageK = [&](int kbid, int buf) {        // linear 16KB chunk copy
    unsigned short* dst = smem + buf * 8192 + w * 512;
    const unsigned short* src = Ksrc + (size_t)kbid * 8192;
#pragma unroll
    for (int c4 = 0; c4 < 4; ++c4)
      stage16(src + c4 * 2048, dst + c4 * 2048);
  };

  const int lo = hi * 512 + q * 16;             // byte offset within frag row

  // resident Q B-frags: lane: query=q, c = 16*ks + 8*hi + j
  const unsigned short* Qb = Qt + ((size_t)b * Nn + q0 + q) * Cn + 8 * hi;
  f16x8 qf[16];
#pragma unroll
  for (int ks = 0; ks < 16; ++ks) qf[ks] = *(const f16x8*)(Qb + 16 * ks);

  auto qkt = [&](int buf) -> f32x16 {           // single-chain QK^T
    const char* KsB = (const char*)smem + buf * 16384;
    f32x16 dd = (f32x16)(0.f);
#pragma unroll
    for (int ks = 0; ks < 16; ++ks)
      dd = MFMA32(*(const f16x8*)(KsB + ks * 1024 + lo), qf[ks], dd);
    return dd;
  };

  stageK(kb0, 0);                               // prologue: 2-ahead
  stageK(kb0 + 1, 1);

  f32x16 acc[4];                                // channels chalf*128 .. +128
#pragma unroll
  for (int ct = 0; ct < 4; ++ct) acc[ct] = (f32x16)(0.f);
  float m = -1e30f, lsum = 0.f;                 // lsum: per-half partial

  asm volatile("s_waitcnt vmcnt(4)" ::: "memory");   // own K0 landed (K1 in flight)
  __builtin_amdgcn_sched_barrier(0);
  __builtin_amdgcn_s_barrier();                 // all waves' K0 landed

  auto body = [&](int t, f32x16& dcur, f32x16& dnx) {
    const unsigned short* vp = Vb + (size_t)(kb0 + t) * 8192;
    // ---- V frags for this iter: all 8, issued first ----
    f16x8 vf[8];
#pragma unroll
    for (int ct = 0; ct < 4; ++ct) {
      vf[2 * ct] = *(const f16x8*)(vp + ct * 1024);
      vf[2 * ct + 1] = *(const f16x8*)(vp + ct * 1024 + 512);
    }
    __builtin_amdgcn_sched_barrier(0);          // keep V issues before K stage
    if (t + 2 < NT) stageK(kb0 + t + 2, (t + 2) % 3);

    // Counted wait: queue = [st(t+1) 4, vf(t) 8, st(t+2) 4]. Publishing
    // buf(t+1) needs only st(t+1) retired -> vmcnt(12); vf(t) stays in
    // flight (compiler waits it at PV). No stage issued when t+2>=NT ->
    // queue = [st(t+1) 4, vf(t) 8] -> vmcnt(8) to still retire st(t+1).
    if (t + 2 < NT)
      asm volatile("s_waitcnt vmcnt(12)" ::: "memory");
    else
      asm volatile("s_waitcnt vmcnt(8)" ::: "memory");
    __builtin_amdgcn_sched_barrier(0);
    __builtin_amdgcn_s_barrier();               // buf(t+1) now block-wide safe

    // ---- QK^T(t+1) on MFMA pipe, overlapped with SM(t) on VALU pipe ----
    if (t + 1 < NT) dnx = qkt((t + 1) % 3);

    // ---- online softmax (log2 domain) on dcur = scores(t) ----
    float u0 = fmaxf(dcur[0], dcur[1]),   u1 = fmaxf(dcur[2], dcur[3]);
    float u2 = fmaxf(dcur[4], dcur[5]),   u3 = fmaxf(dcur[6], dcur[7]);
    float u4 = fmaxf(dcur[8], dcur[9]),   u5 = fmaxf(dcur[10], dcur[11]);
    float u6 = fmaxf(dcur[12], dcur[13]), u7 = fmaxf(dcur[14], dcur[15]);
    float mx = fmaxf(fmaxf(fmaxf(u0, u1), fmaxf(u2, u3)),
                     fmaxf(fmaxf(u4, u5), fmaxf(u6, u7)));
    {                                           // cross-half max (order-robust)
      float mc = mx;
      pl32swapf(mc, mx);
      mx = fmaxf(mc, mx);
    }
    if (__any(mx > m + 12.f)) {                 // defer-max (THR=12 log2)
      float mnew = fmaxf(m, mx);
      float alpha = __builtin_exp2f(m - mnew);
      m = mnew;
      lsum *= alpha;
#pragma unroll
      for (int ct = 0; ct < 4; ++ct)
#pragma unroll
        for (int r = 0; r < 16; ++r) acc[ct][r] *= alpha;
    }
    float p[16];
#pragma unroll
    for (int r = 0; r < 16; ++r) p[r] = __builtin_exp2f(dcur[r] - m);
    float cs = 0.f;
#pragma unroll
    for (int r = 0; r < 16; ++r) cs += p[r];
    lsum += cs;                                 // per-half partial (no shfl)

    // ---- P -> B-frags: swap(A0,A2) yields (pb0.u[0], pb0.u[2]) etc ----
    unsigned A0 = pk2(p[0], p[1]), A1 = pk2(p[2], p[3]);
    unsigned A2 = pk2(p[4], p[5]), A3 = pk2(p[6], p[7]);
    unsigned A4 = pk2(p[8], p[9]), A5 = pk2(p[10], p[11]);
    unsigned A6 = pk2(p[12], p[13]), A7 = pk2(p[14], p[15]);
    pl32swap(A0, A2);
    pl32swap(A1, A3);
    pl32swap(A4, A6);
    pl32swap(A5, A7);
    union { unsigned u[4]; f16x8 v; } pb0, pb1;
    pb0.u[0] = A0; pb0.u[1] = A1; pb0.u[2] = A2; pb0.u[3] = A3;
    pb1.u[0] = A4; pb1.u[1] = A5; pb1.u[2] = A6; pb1.u[3] = A7;

    // ---- PV: 4 c-tiles of this wave's c-half, V from registers ----
    __builtin_amdgcn_s_setprio(1);
    acc[0] = MFMA32(vf[0], pb0.v, acc[0]);
    acc[0] = MFMA32(vf[1], pb1.v, acc[0]);
    acc[1] = MFMA32(vf[2], pb0.v, acc[1]);
    acc[1] = MFMA32(vf[3], pb1.v, acc[1]);
    acc[2] = MFMA32(vf[4], pb0.v, acc[2]);
    acc[2] = MFMA32(vf[5], pb1.v, acc[2]);
    acc[3] = MFMA32(vf[6], pb0.v, acc[3]);
    acc[3] = MFMA32(vf[7], pb1.v, acc[3]);
    __builtin_amdgcn_s_setprio(0);
  };

  f32x16 dA = qkt(0), dB;                       // scores for tile 0
  for (int t = 0; t < NT; t += 2) {             // NT even: no tail
    body(t, dA, dB);
    body(t + 1, dB, dA);
  }

  // ---- epilogue: combine half-sums (order-robust), O_s = acc/lsum ----
  {
    float lc = lsum;
    pl32swapf(lc, lsum);
    lsum += lc;
  }
  const float rl = 1.f / lsum;
  unsigned short* Pb = P + (size_t)(s * Bn + b) * Cn * Nn;
#pragma unroll
  for (int ct = 0; ct < 4; ++ct)
#pragma unroll
    for (int r = 0; r < 16; ++r) {
      int c = 32 * (chalf * 4 + ct) + (r & 3) + 8 * (r >> 2) + 4 * hi;
      Pb[(size_t)c * Nn + q0 + q] = f2h(acc[ct][r] * rl);
    }
  if (!hi && !chalf)
    *(float2*)&ml[((size_t)(s * Bn + b) * Nn + q0 + q) * 2] = make_float2(m, lsum);
}

// ---------------- combine partials + residual (dynamic splits <= 4) --------
// out = x + sum_s w_s * O_s,  w_s = 2^(m_s - M) * l_s / sum(2^(m_s-M) l_s).
__global__ __launch_bounds__(256) void combine_k(
    const float* __restrict__ x, const unsigned short* __restrict__ P,
    const float* __restrict__ ml, float* __restrict__ out, int splits) {
  __shared__ float sc[4][32];
  const int tpb = Nn / 32;                      // 72
  const int b = blockIdx.x / tpb;
  const int n0 = (blockIdx.x - b * tpb) * 32;
  const int t = threadIdx.x;
  if (t < 32) {
    const int n = n0 + t;
    const size_t sstr = (size_t)Bn * Nn * 2;
    const float* mlb = ml + ((size_t)b * Nn + n) * 2;
    float M = -1e30f;
    for (int s2 = 0; s2 < splits; ++s2) M = fmaxf(M, mlb[s2 * sstr]);
    float den = 0.f;
    for (int s2 = 0; s2 < splits; ++s2) {
      float g = __builtin_exp2f(mlb[s2 * sstr] - M) * mlb[s2 * sstr + 1];
      sc[s2][t] = g;
      den += g;
    }
    float rden = 1.f / den;
    for (int s2 = 0; s2 < splits; ++s2) sc[s2][t] *= rden;
  }
  __syncthreads();
  const int nl4 = (t & 7) * 4, c0 = t >> 3;
  const size_t pstr = (size_t)Bn * Cn * Nn;     // shorts per split
  const float* xb = x + (size_t)b * Cn * Nn;
  float* ob = out + (size_t)b * Cn * Nn;
#pragma unroll
  for (int k = 0; k < 8; ++k) {
    const int c = c0 + 32 * k;
    const unsigned short* Pp = P + ((size_t)b * Cn + c) * Nn + n0 + nl4;
    f32x4 a = {0.f, 0.f, 0.f, 0.f};
    for (int s2 = 0; s2 < splits; ++s2) {
      ushort4 ph = *(const ushort4*)(Pp + s2 * pstr);
      f32x4 pv = {h2f(ph.x), h2f(ph.y), h2f(ph.z), h2f(ph.w)};
      f32x4 sw = {sc[s2][nl4 + 0], sc[s2][nl4 + 1], sc[s2][nl4 + 2], sc[s2][nl4 + 3]};
      a += sw * pv;
    }
    f32x4 xv = *(const f32x4*)(xb + (size_t)c * Nn + n0 + nl4);
    *(f32x4*)(ob + (size_t)c * Nn + n0 + nl4) = xv + a;
  }
}

extern "C" void kernel_launch(void* const* d_in, const int* in_sizes, int n_in,
                              void* d_out, int out_size, void* d_ws, size_t ws_size,
                              hipStream_t stream) {
  const float* x = (const float*)d_in[0];
  const float* wq = (const float*)d_in[1];
  const float* wk = (const float*)d_in[2];
  const float* wv = (const float*)d_in[3];
  float* out = (float*)d_out;

  unsigned short* wqb = (unsigned short*)d_ws;
  unsigned short* wkb = wqb + Cn * Cn;
  unsigned short* wvb = wkb + Cn * Cn;
  unsigned short* Qt = wvb + Cn * Cn;
  unsigned short* Ksw = Qt + (size_t)Bn * Nn * Cn;
  unsigned short* Vsw = Ksw + (size_t)Bn * Nn * Cn;
  unsigned short* P = Vsw + (size_t)Bn * Nn * Cn;

  const size_t baseB = (size_t)(3 * Cn * Cn + 3 * (size_t)Bn * Nn * Cn) * 2;
  const size_t perSplitB = (size_t)Bn * Nn * Cn * 2 + (size_t)Bn * Nn * 2 * 4;

  int splits = 1;
  if (baseB + 4 * perSplitB <= ws_size) splits = 4;
  else if (baseB + 2 * perSplitB <= ws_size) splits = 2;

  float* ml = (float*)(P + (size_t)splits * Bn * Nn * Cn);

  hipLaunchKernelGGL(cvt_w, dim3(3 * Cn * Cn / 256), dim3(256), 0, stream, wq, wk, wv, wqb);
  hipLaunchKernelGGL(qkv_proj, dim3(Nn / 32, Bn), dim3(256), 0, stream,
                     x, wqb, wkb, wvb, Qt, Ksw, Vsw);
  hipLaunchKernelGGL(attn_split, dim3(Bn * splits * 36), dim3(256), 0, stream,
                     Qt, Ksw, Vsw, P, ml, splits);
  hipLaunchKernelGGL(combine_k, dim3(Bn * Nn / 32), dim3(256), 0, stream,
                     x, P, ml, out, splits);
}

// Round 24
// 148.973 us; speedup vs baseline: 1.1675x; 1.0027x over previous
//
#include <hip/hip_runtime.h>
#include <hip/hip_bf16.h>

// SelfAttention: x[8,256,48,48] fp32; wq/wk/wv[256,256] fp32.
// out = x + attn(softmax(q^T k), v). B=8, C=256, N=2304. fp16 MFMA path.
//
// R23 post-mortem: LDS weight staging WIN (total 160.4 -> 149.4, non-attn
// ~51 -> ~40us). attn at latency plateau (established R14-R21). R24: widen
// combine_k P reads to ushort8 (16B/lane, G13 sweet spot); x/out as 2x
// f32x4. Same work, half the P-load instructions. Everything else = R23.
//
// K_swz[kb][ks 16][hi 2][key 32][j 8]: short off = kb*8192+ks*512+hi*256+key*8+j
// V_swz[kb][ct 8][kh 2][hi 2][c 32][j 8]: off = kb*8192+ct*1024+kh*512+hi*256+c*8+j
// weights frag-ordered: off = ot*4096 + ks*512 + g*128 + i*8 + j
// ws: wq/wk/wv fp16 [65536 ea]; Qt [B*N*C] token-major; Ksw,Vsw [B*N*C];
//     P fp16 [splits][B][C][N]; ml f32 [splits][B][N][2].

#define DEVI __device__ __forceinline__

typedef _Float16 f16x8 __attribute__((ext_vector_type(8)));
typedef unsigned short u16x8 __attribute__((ext_vector_type(8)));
typedef float f32x4 __attribute__((ext_vector_type(4)));
typedef float f32x16 __attribute__((ext_vector_type(16)));

constexpr int Bn = 8, Cn = 256, Nn = 48 * 48;   // 2304

#if defined(__has_builtin)
#if __has_builtin(__builtin_amdgcn_permlane32_swap)
#define HAVE_PL32 1
#endif
#endif

DEVI unsigned short f2h(float f) {
  _Float16 h = (_Float16)f;
  return __builtin_bit_cast(unsigned short, h);
}
DEVI float h2f(unsigned short u) {
  return (float)__builtin_bit_cast(_Float16, u);
}
DEVI unsigned pk2(float a, float b) {           // pack 2 f32 -> f16x2 (RTZ)
  auto h = __builtin_amdgcn_cvt_pkrtz(a, b);
  return __builtin_bit_cast(unsigned, h);
}
DEVI void stage16(const unsigned short* g, unsigned short* l) {
  __builtin_amdgcn_global_load_lds(
      (const __attribute__((address_space(1))) void*)g,
      (__attribute__((address_space(3))) void*)l, 16, 0, 0);
}
// permlane32_swap(a,b): a' = {a.lo, b.lo}; b' = {a.hi, b.hi}
DEVI void pl32swap(unsigned& a, unsigned& b) {
#ifdef HAVE_PL32
  auto r = __builtin_amdgcn_permlane32_swap(a, b, false, false);
  a = r[0];
  b = r[1];
#else
  unsigned sa = __shfl_xor(a, 32), sb = __shfl_xor(b, 32);
  bool hb = (threadIdx.x & 32) != 0;
  a = hb ? sb : a;
  b = hb ? b : sa;
#endif
}
DEVI void pl32swapf(float& a, float& b) {
  unsigned ua = __builtin_bit_cast(unsigned, a);
  unsigned ub = __builtin_bit_cast(unsigned, b);
  pl32swap(ua, ub);
  a = __builtin_bit_cast(float, ua);
  b = __builtin_bit_cast(float, ub);
}

#define MFMA16(a, b, c) __builtin_amdgcn_mfma_f32_16x16x32_f16((a), (b), (c), 0, 0, 0)
#define MFMA32(a, b, c) __builtin_amdgcn_mfma_f32_32x32x16_f16((a), (b), (c), 0, 0, 0)

// ---- weights -> fp16, FRAG-ORDERED: dst[ot*4096 + ks*512 + g*128 + i*8 + j]
//      = w[oc = 16ot + i][c = 32ks + 8g + j]  (wq pre-scaled by log2e)
__global__ __launch_bounds__(256) void cvt_w(const float* __restrict__ wq,
                                             const float* __restrict__ wk,
                                             const float* __restrict__ wv,
                                             unsigned short* __restrict__ o) {
  int idx = blockIdx.x * 256 + threadIdx.x;     // 3*65536 total
  int mat = idx >> 16, off = idx & 65535;
  const float* s = (mat == 0) ? wq : (mat == 1) ? wk : wv;
  int ot = off >> 12, ks = (off >> 9) & 7, g = (off >> 7) & 3;
  int i = (off >> 3) & 15, j = off & 7;
  float v = s[(ot * 16 + i) * Cn + ks * 32 + g * 8 + j];
  if (mat == 0) v *= 1.44269504f;               // exp2-domain softmax
  o[idx] = f2h(v);
}

// ---------------- QKV projection (LDS-staged weights, n-tile 32) -----------
// grid (N/32, B) = (72, 8), 256 thr = 4 waves. th = w&1 (token half).
// 24 steps: e<16: {wq[e], wk[e]}: w0,w1 -> Q[e] th0,1; w2,w3 -> K[e] th0,1.
//           e>=16: {wv[2(e-16)], wv[2(e-16)+1]}: wave pair (w>>1) per tile.
// 8KB tiles staged once per block into 2-deep ring (32KB); stage AFTER the
// step __syncthreads (implicit vmcnt(0) publishes st(e); barrier separates
// compute(e-1) reads from st(e+1) writes).
__global__ __launch_bounds__(256) void qkv_proj(
    const float* __restrict__ x,
    const unsigned short* __restrict__ wqb, const unsigned short* __restrict__ wkb,
    const unsigned short* __restrict__ wvb,
    unsigned short* __restrict__ Qt, unsigned short* __restrict__ Ksw,
    unsigned short* __restrict__ Vsw) {
  __shared__ unsigned short xT[32][264];        // [token][c], +8 pad (16.9 KB)
  __shared__ unsigned short wbuf[2][2][4096];   // 2 bufs x 2 tiles x 8KB (32 KB)
  const int tid = threadIdx.x;
  const int n0 = blockIdx.x * 32;
  const int b = blockIdx.y;
  const float* xb = x + (size_t)b * Cn * Nn;
  {
    int c0 = tid >> 3;
    int nn = (tid & 7) * 4;
#pragma unroll
    for (int it = 0; it < 8; ++it) {
      int c = c0 + 32 * it;
      float4 v = *(const float4*)(xb + (size_t)c * Nn + n0 + nn);
      xT[nn + 0][c] = f2h(v.x);
      xT[nn + 1][c] = f2h(v.y);
      xT[nn + 2][c] = f2h(v.z);
      xT[nn + 3][c] = f2h(v.w);
    }
  }
  const int lane = tid & 63, w = tid >> 6;
  const int i = lane & 15, g = lane >> 4;
  const int th = w & 1;                         // token half
  const int wlo = g * 128 + i * 8;              // frag-ordered lane offset

  // stage step e into buf: 2 tiles x 8KB; wave w covers shorts [w*1024,+1024)
  // of each tile via 2 stage16 (each = 64 lanes x 16B = 512 shorts).
  auto stageW = [&](int e, int buf) {
    const unsigned short* s0;
    const unsigned short* s1;
    if (e < 16) {
      s0 = wqb + e * 4096;
      s1 = wkb + e * 4096;
    } else {
      int ee = e - 16;
      s0 = wvb + (2 * ee) * 4096;
      s1 = wvb + (2 * ee + 1) * 4096;
    }
    stage16(s0 + w * 1024 + lane * 8,       &wbuf[buf][0][w * 1024]);
    stage16(s0 + w * 1024 + 512 + lane * 8, &wbuf[buf][0][w * 1024 + 512]);
    stage16(s1 + w * 1024 + lane * 8,       &wbuf[buf][1][w * 1024]);
    stage16(s1 + w * 1024 + 512 + lane * 8, &wbuf[buf][1][w * 1024 + 512]);
  };

  stageW(0, 0);                                 // prologue
  __syncthreads();                              // drains xT writes + st(0)

  f16x8 xf[8];                                  // x^T frags for tokens th*16..+15
#pragma unroll
  for (int ks = 0; ks < 8; ++ks)
    xf[ks] = *(const f16x8*)(&xT[th * 16 + i][32 * ks + 8 * g]);

  const int kb0 = n0 >> 5;                      // == blockIdx.x (32-token chunk)
  const size_t tokbase = (size_t)b * Nn + n0 + th * 16;
  unsigned short* kout = Ksw + (size_t)b * Nn * Cn + (size_t)kb0 * 8192
                       + ((i >> 3) & 1) * 256 + (i & 7);
  const int keyb = th * 16 + 4 * g;
  unsigned short* vout = Vsw + (size_t)b * Nn * Cn + (size_t)kb0 * 8192
                       + th * 512 + ((i >> 3) & 1) * 256 + (i & 7);

  for (int e = 0; e < 24; ++e) {
    if (e) __syncthreads();                     // vmcnt(0): st(e) published;
                                                // all waves done compute(e-1)
    if (e + 1 < 24) stageW(e + 1, (e + 1) & 1); // safe: slot's readers done

    const unsigned short* wr = &wbuf[e & 1][w >> 1][wlo];
    if (e < 16) {                               // phase 1: Q (w<2) / K (w>=2)
      const int ot = e;
      f32x4 acc = {0.f, 0.f, 0.f, 0.f};
#pragma unroll
      for (int ks = 0; ks < 8; ++ks)
        acc = MFMA16(xf[ks], *(const f16x8*)(wr + 512 * ks), acc);
      if (w < 2) {
#pragma unroll
        for (int r = 0; r < 4; ++r)
          Qt[(tokbase + 4 * g + r) * Cn + ot * 16 + i] = f2h(acc[r]);
      } else {
#pragma unroll
        for (int r = 0; r < 4; ++r)
          kout[ot * 512 + (keyb + r) * 8] = f2h(acc[r]);
      }
    } else {                                    // phase 2: V
      const int ot = 2 * (e - 16) + (w >> 1);
      f32x4 acc = {0.f, 0.f, 0.f, 0.f};
#pragma unroll
      for (int ks = 0; ks < 8; ++ks)
        acc = MFMA16(*(const f16x8*)(wr + 512 * ks), xf[ks], acc);
#pragma unroll
      for (int r = 0; r < 4; ++r) {
        int c = ot * 16 + 4 * g + r;
        vout[(c >> 5) * 1024 + (c & 31) * 8] = f2h(acc[r]);
      }
    }
  }
}

// ---- flash attention: split-K, K 3-buf LDS, V reg-streamed, T15 x2 --------
// grid Bn*splits*36, 256 thr = 4 waves = 2 q-tiles(32q) x 2 c-halves(128c).
// LDS 48KB = 3 x 16KB K bufs, staged 2-ahead. Mid-iter barrier after COUNTED
// vmcnt(12): publishes st(t+1) without draining vf(t) (V waits at PV only).
__global__ __launch_bounds__(256, 2) void attn_split(
    const unsigned short* __restrict__ Qt, const unsigned short* __restrict__ Ksw,
    const unsigned short* __restrict__ Vsw,
    unsigned short* __restrict__ P, float* __restrict__ ml, int splits) {
  __shared__ unsigned short smem[24576];        // 48 KB
  const int nblk = gridDim.x;                   // divisible by 8
  const int cpx = nblk >> 3;
  const int swz = (blockIdx.x & 7) * cpx + (blockIdx.x >> 3);  // XCD chunked
  const int per_b = splits * 36;
  const int b = swz / per_b;
  const int rem = swz - b * per_b;
  const int s = rem / 36;
  const int qt = rem - s * 36;
  const int n0 = qt * 64;
  const int kn = Nn / splits;
  const int kb0 = (s * kn) >> 5;                // first 32-key chunk id
  const int NT = kn / 32;                       // 18 at splits=4 (even)

  const int tid = threadIdx.x, lane = tid & 63, w = tid >> 6;
  const int q = lane & 31, hi = lane >> 5;
  const int qtile = w & 1, chalf = w >> 1;
  const int q0 = n0 + qtile * 32;

  const unsigned short* Ksrc = Ksw + (size_t)b * Nn * Cn + tid * 8;
  const unsigned short* Vb = Vsw + (size_t)b * Nn * Cn + hi * 256 + q * 8
                           + (size_t)chalf * 4096;

  auto stageK = [&](int kbid, int buf) {        // linear 16KB chunk copy
    unsigned short* dst = smem + buf * 8192 + w * 512;
    const unsigned short* src = Ksrc + (size_t)kbid * 8192;
#pragma unroll
    for (int c4 = 0; c4 < 4; ++c4)
      stage16(src + c4 * 2048, dst + c4 * 2048);
  };

  const int lo = hi * 512 + q * 16;             // byte offset within frag row

  // resident Q B-frags: lane: query=q, c = 16*ks + 8*hi + j
  const unsigned short* Qb = Qt + ((size_t)b * Nn + q0 + q) * Cn + 8 * hi;
  f16x8 qf[16];
#pragma unroll
  for (int ks = 0; ks < 16; ++ks) qf[ks] = *(const f16x8*)(Qb + 16 * ks);

  auto qkt = [&](int buf) -> f32x16 {           // single-chain QK^T
    const char* KsB = (const char*)smem + buf * 16384;
    f32x16 dd = (f32x16)(0.f);
#pragma unroll
    for (int ks = 0; ks < 16; ++ks)
      dd = MFMA32(*(const f16x8*)(KsB + ks * 1024 + lo), qf[ks], dd);
    return dd;
  };

  stageK(kb0, 0);                               // prologue: 2-ahead
  stageK(kb0 + 1, 1);

  f32x16 acc[4];                                // channels chalf*128 .. +128
#pragma unroll
  for (int ct = 0; ct < 4; ++ct) acc[ct] = (f32x16)(0.f);
  float m = -1e30f, lsum = 0.f;                 // lsum: per-half partial

  asm volatile("s_waitcnt vmcnt(4)" ::: "memory");   // own K0 landed (K1 in flight)
  __builtin_amdgcn_sched_barrier(0);
  __builtin_amdgcn_s_barrier();                 // all waves' K0 landed

  auto body = [&](int t, f32x16& dcur, f32x16& dnx) {
    const unsigned short* vp = Vb + (size_t)(kb0 + t) * 8192;
    // ---- V frags for this iter: all 8, issued first ----
    f16x8 vf[8];
#pragma unroll
    for (int ct = 0; ct < 4; ++ct) {
      vf[2 * ct] = *(const f16x8*)(vp + ct * 1024);
      vf[2 * ct + 1] = *(const f16x8*)(vp + ct * 1024 + 512);
    }
    __builtin_amdgcn_sched_barrier(0);          // keep V issues before K stage
    if (t + 2 < NT) stageK(kb0 + t + 2, (t + 2) % 3);

    // Counted wait: queue = [st(t+1) 4, vf(t) 8, st(t+2) 4]. Publishing
    // buf(t+1) needs only st(t+1) retired -> vmcnt(12); vf(t) stays in
    // flight (compiler waits it at PV). No stage issued when t+2>=NT ->
    // queue = [st(t+1) 4, vf(t) 8] -> vmcnt(8) to still retire st(t+1).
    if (t + 2 < NT)
      asm volatile("s_waitcnt vmcnt(12)" ::: "memory");
    else
      asm volatile("s_waitcnt vmcnt(8)" ::: "memory");
    __builtin_amdgcn_sched_barrier(0);
    __builtin_amdgcn_s_barrier();               // buf(t+1) now block-wide safe

    // ---- QK^T(t+1) on MFMA pipe, overlapped with SM(t) on VALU pipe ----
    if (t + 1 < NT) dnx = qkt((t + 1) % 3);

    // ---- online softmax (log2 domain) on dcur = scores(t) ----
    float u0 = fmaxf(dcur[0], dcur[1]),   u1 = fmaxf(dcur[2], dcur[3]);
    float u2 = fmaxf(dcur[4], dcur[5]),   u3 = fmaxf(dcur[6], dcur[7]);
    float u4 = fmaxf(dcur[8], dcur[9]),   u5 = fmaxf(dcur[10], dcur[11]);
    float u6 = fmaxf(dcur[12], dcur[13]), u7 = fmaxf(dcur[14], dcur[15]);
    float mx = fmaxf(fmaxf(fmaxf(u0, u1), fmaxf(u2, u3)),
                     fmaxf(fmaxf(u4, u5), fmaxf(u6, u7)));
    {                                           // cross-half max (order-robust)
      float mc = mx;
      pl32swapf(mc, mx);
      mx = fmaxf(mc, mx);
    }
    if (__any(mx > m + 12.f)) {                 // defer-max (THR=12 log2)
      float mnew = fmaxf(m, mx);
      float alpha = __builtin_exp2f(m - mnew);
      m = mnew;
      lsum *= alpha;
#pragma unroll
      for (int ct = 0; ct < 4; ++ct)
#pragma unroll
        for (int r = 0; r < 16; ++r) acc[ct][r] *= alpha;
    }
    float p[16];
#pragma unroll
    for (int r = 0; r < 16; ++r) p[r] = __builtin_exp2f(dcur[r] - m);
    float cs = 0.f;
#pragma unroll
    for (int r = 0; r < 16; ++r) cs += p[r];
    lsum += cs;                                 // per-half partial (no shfl)

    // ---- P -> B-frags: swap(A0,A2) yields (pb0.u[0], pb0.u[2]) etc ----
    unsigned A0 = pk2(p[0], p[1]), A1 = pk2(p[2], p[3]);
    unsigned A2 = pk2(p[4], p[5]), A3 = pk2(p[6], p[7]);
    unsigned A4 = pk2(p[8], p[9]), A5 = pk2(p[10], p[11]);
    unsigned A6 = pk2(p[12], p[13]), A7 = pk2(p[14], p[15]);
    pl32swap(A0, A2);
    pl32swap(A1, A3);
    pl32swap(A4, A6);
    pl32swap(A5, A7);
    union { unsigned u[4]; f16x8 v; } pb0, pb1;
    pb0.u[0] = A0; pb0.u[1] = A1; pb0.u[2] = A2; pb0.u[3] = A3;
    pb1.u[0] = A4; pb1.u[1] = A5; pb1.u[2] = A6; pb1.u[3] = A7;

    // ---- PV: 4 c-tiles of this wave's c-half, V from registers ----
    __builtin_amdgcn_s_setprio(1);
    acc[0] = MFMA32(vf[0], pb0.v, acc[0]);
    acc[0] = MFMA32(vf[1], pb1.v, acc[0]);
    acc[1] = MFMA32(vf[2], pb0.v, acc[1]);
    acc[1] = MFMA32(vf[3], pb1.v, acc[1]);
    acc[2] = MFMA32(vf[4], pb0.v, acc[2]);
    acc[2] = MFMA32(vf[5], pb1.v, acc[2]);
    acc[3] = MFMA32(vf[6], pb0.v, acc[3]);
    acc[3] = MFMA32(vf[7], pb1.v, acc[3]);
    __builtin_amdgcn_s_setprio(0);
  };

  f32x16 dA = qkt(0), dB;                       // scores for tile 0
  for (int t = 0; t < NT; t += 2) {             // NT even: no tail
    body(t, dA, dB);
    body(t + 1, dB, dA);
  }

  // ---- epilogue: combine half-sums (order-robust), O_s = acc/lsum ----
  {
    float lc = lsum;
    pl32swapf(lc, lsum);
    lsum += lc;
  }
  const float rl = 1.f / lsum;
  unsigned short* Pb = P + (size_t)(s * Bn + b) * Cn * Nn;
#pragma unroll
  for (int ct = 0; ct < 4; ++ct)
#pragma unroll
    for (int r = 0; r < 16; ++r) {
      int c = 32 * (chalf * 4 + ct) + (r & 3) + 8 * (r >> 2) + 4 * hi;
      Pb[(size_t)c * Nn + q0 + q] = f2h(acc[ct][r] * rl);
    }
  if (!hi && !chalf)
    *(float2*)&ml[((size_t)(s * Bn + b) * Nn + q0 + q) * 2] = make_float2(m, lsum);
}

// ---------------- combine partials + residual (dynamic splits <= 4) --------
// out = x + sum_s w_s * O_s,  w_s = 2^(m_s - M) * l_s / sum(2^(m_s-M) l_s).
// R24: 16B (ushort8) P reads; thread owns 8 n x 64 c-groups x 4 iters.
__global__ __launch_bounds__(256) void combine_k(
    const float* __restrict__ x, const unsigned short* __restrict__ P,
    const float* __restrict__ ml, float* __restrict__ out, int splits) {
  __shared__ float sc[4][32];
  const int tpb = Nn / 32;                      // 72
  const int b = blockIdx.x / tpb;
  const int n0 = (blockIdx.x - b * tpb) * 32;
  const int t = threadIdx.x;
  if (t < 32) {
    const int n = n0 + t;
    const size_t sstr = (size_t)Bn * Nn * 2;
    const float* mlb = ml + ((size_t)b * Nn + n) * 2;
    float M = -1e30f;
    for (int s2 = 0; s2 < splits; ++s2) M = fmaxf(M, mlb[s2 * sstr]);
    float den = 0.f;
    for (int s2 = 0; s2 < splits; ++s2) {
      float g = __builtin_exp2f(mlb[s2 * sstr] - M) * mlb[s2 * sstr + 1];
      sc[s2][t] = g;
      den += g;
    }
    float rden = 1.f / den;
    for (int s2 = 0; s2 < splits; ++s2) sc[s2][t] *= rden;
  }
  __syncthreads();
  const int nl8 = (t & 3) * 8, c0 = t >> 2;     // 64 c-groups x 8 n
  const size_t pstr = (size_t)Bn * Cn * Nn;     // shorts per split
  const float* xb = x + (size_t)b * Cn * Nn;
  float* ob = out + (size_t)b * Cn * Nn;
  float sw[4][8];
#pragma unroll
  for (int s2 = 0; s2 < 4; ++s2)
#pragma unroll
    for (int j = 0; j < 8; ++j) sw[s2][j] = sc[s2][nl8 + j];
#pragma unroll
  for (int k = 0; k < 4; ++k) {
    const int c = c0 + 64 * k;
    const unsigned short* Pp = P + ((size_t)b * Cn + c) * Nn + n0 + nl8;
    float a[8] = {0.f, 0.f, 0.f, 0.f, 0.f, 0.f, 0.f, 0.f};
    for (int s2 = 0; s2 < splits; ++s2) {
      u16x8 ph = *(const u16x8*)(Pp + s2 * pstr);
#pragma unroll
      for (int j = 0; j < 8; ++j) a[j] += sw[s2][j] * h2f(ph[j]);
    }
    const float* xp = xb + (size_t)c * Nn + n0 + nl8;
    float* op = ob + (size_t)c * Nn + n0 + nl8;
    f32x4 x0 = *(const f32x4*)(xp);
    f32x4 x1 = *(const f32x4*)(xp + 4);
    f32x4 o0 = {x0[0] + a[0], x0[1] + a[1], x0[2] + a[2], x0[3] + a[3]};
    f32x4 o1 = {x1[0] + a[4], x1[1] + a[5], x1[2] + a[6], x1[3] + a[7]};
    *(f32x4*)(op) = o0;
    *(f32x4*)(op + 4) = o1;
  }
}

extern "C" void kernel_launch(void* const* d_in, const int* in_sizes, int n_in,
                              void* d_out, int out_size, void* d_ws, size_t ws_size,
                              hipStream_t stream) {
  const float* x = (const float*)d_in[0];
  const float* wq = (const float*)d_in[1];
  const float* wk = (const float*)d_in[2];
  const float* wv = (const float*)d_in[3];
  float* out = (float*)d_out;

  unsigned short* wqb = (unsigned short*)d_ws;
  unsigned short* wkb = wqb + Cn * Cn;
  unsigned short* wvb = wkb + Cn * Cn;
  unsigned short* Qt = wvb + Cn * Cn;
  unsigned short* Ksw = Qt + (size_t)Bn * Nn * Cn;
  unsigned short* Vsw = Ksw + (size_t)Bn * Nn * Cn;
  unsigned short* P = Vsw + (size_t)Bn * Nn * Cn;

  const size_t baseB = (size_t)(3 * Cn * Cn + 3 * (size_t)Bn * Nn * Cn) * 2;
  const size_t perSplitB = (size_t)Bn * Nn * Cn * 2 + (size_t)Bn * Nn * 2 * 4;

  int splits = 1;
  if (baseB + 4 * perSplitB <= ws_size) splits = 4;
  else if (baseB + 2 * perSplitB <= ws_size) splits = 2;

  float* ml = (float*)(P + (size_t)splits * Bn * Nn * Cn);

  hipLaunchKernelGGL(cvt_w, dim3(3 * Cn * Cn / 256), dim3(256), 0, stream, wq, wk, wv, wqb);
  hipLaunchKernelGGL(qkv_proj, dim3(Nn / 32, Bn), dim3(256), 0, stream,
                     x, wqb, wkb, wvb, Qt, Ksw, Vsw);
  hipLaunchKernelGGL(attn_split, dim3(Bn * splits * 36), dim3(256), 0, stream,
                     Qt, Ksw, Vsw, P, ml, splits);
  hipLaunchKernelGGL(combine_k, dim3(Bn * Nn / 32), dim3(256), 0, stream,
                     x, P, ml, out, splits);
}